// Round 1
// baseline (1715.226 us; speedup 1.0000x reference)
//
#include <hip/hip_runtime.h>
#include <math.h>

#define NN 50000
#define NE 800000

// ---------------- degree / norm ----------------
__global__ void k_deg(const int* __restrict__ ei, float* __restrict__ deg) {
    int e = blockIdx.x * 256 + threadIdx.x;
    if (e < NE) atomicAdd(&deg[ei[e]], 1.0f);
}

__global__ void k_dis(const float* __restrict__ deg, float* __restrict__ dis) {
    int i = blockIdx.x * 256 + threadIdx.x;
    if (i < NN) {
        float d = deg[i];
        dis[i] = d > 0.0f ? 1.0f / sqrtf(d) : 0.0f;
    }
}

__global__ void k_norm(const int* __restrict__ ei, const float* __restrict__ dis,
                       float* __restrict__ norm) {
    int e = blockIdx.x * 256 + threadIdx.x;
    if (e < NE) {
        int s = ei[e], d = ei[NE + e];
        norm[e] = -(dis[s] * dis[d]);
    }
}

// ---------------- layer1 scatter: tx1[dst,f] += x[src,f]*norm[e], f<58 --------
__global__ void k_scat58(const int* __restrict__ ei, const float* __restrict__ x,
                         const float* __restrict__ norm, float* __restrict__ tx1) {
    int t = blockIdx.x * 256 + threadIdx.x;
    int e = t >> 6;
    int f = t & 63;
    if (e < NE && f < 58) {
        int s = ei[e], d = ei[NE + e];
        atomicAdd(&tx1[d * 58 + f], x[s * 58 + f] * norm[e]);
    }
}

// ---------------- h = relu(x@W0 + tx1@W1 + b)  [N,58]->[N,300] ----------------
__global__ __launch_bounds__(256) void k_gemm1(const float* __restrict__ x,
                                               const float* __restrict__ tx1,
                                               const float* __restrict__ W0,
                                               const float* __restrict__ W1,
                                               const float* __restrict__ b,
                                               float* __restrict__ h) {
    __shared__ float Ax[16][58];
    __shared__ float At[16][58];
    int row0 = blockIdx.x * 16;
    for (int idx = threadIdx.x; idx < 16 * 58; idx += 256) {
        Ax[idx / 58][idx % 58] = x[row0 * 58 + idx];
        At[idx / 58][idx % 58] = tx1[row0 * 58 + idx];
    }
    __syncthreads();
    for (int idx = threadIdx.x; idx < 16 * 300; idx += 256) {
        int r = idx / 300, c = idx % 300;
        float acc = b[c];
        for (int k = 0; k < 58; k++)
            acc += Ax[r][k] * W0[k * 300 + c] + At[r][k] * W1[k * 300 + c];
        h[(row0 + r) * 300 + c] = fmaxf(acc, 0.0f);
    }
}

// ---------------- hw = h @ W2_1  [N,300]->[N,100] ----------------
__global__ __launch_bounds__(256) void k_gemm_hw(const float* __restrict__ h,
                                                 const float* __restrict__ W,
                                                 float* __restrict__ hw) {
    __shared__ float Ah[16][300];
    int row0 = blockIdx.x * 16;
    for (int idx = threadIdx.x; idx < 16 * 300; idx += 256)
        Ah[idx / 300][idx % 300] = h[row0 * 300 + idx];
    __syncthreads();
    for (int idx = threadIdx.x; idx < 16 * 100; idx += 256) {
        int r = idx / 100, c = idx % 100;
        float acc = 0.0f;
        for (int k = 0; k < 300; k++) acc += Ah[r][k] * W[k * 100 + c];
        hw[(row0 + r) * 100 + c] = acc;
    }
}

// ---------------- layer2 scatter: tx2[dst,f] += hw[src,f]*norm[e], f<100 ------
__global__ void k_scat100(const int* __restrict__ ei, const float* __restrict__ hw,
                          const float* __restrict__ norm, float* __restrict__ tx2) {
    int t = blockIdx.x * 256 + threadIdx.x;
    int e = t >> 7;
    int f = t & 127;
    if (e < NE && f < 100) {
        int s = ei[e], d = ei[NE + e];
        atomicAdd(&tx2[d * 100 + f], hw[s * 100 + f] * norm[e]);
    }
}

// ---------------- x1 = relu(h@W2_0 + tx2 + b2) ----------------
__global__ __launch_bounds__(256) void k_gemm_x1(const float* __restrict__ h,
                                                 const float* __restrict__ W,
                                                 const float* __restrict__ tx2,
                                                 const float* __restrict__ b,
                                                 float* __restrict__ x1) {
    __shared__ float Ah[16][300];
    int row0 = blockIdx.x * 16;
    for (int idx = threadIdx.x; idx < 16 * 300; idx += 256)
        Ah[idx / 300][idx % 300] = h[row0 * 300 + idx];
    __syncthreads();
    for (int idx = threadIdx.x; idx < 16 * 100; idx += 256) {
        int r = idx / 100, c = idx % 100;
        float acc = b[c];
        for (int k = 0; k < 300; k++) acc += Ah[r][k] * W[k * 100 + c];
        acc += tx2[(row0 + r) * 100 + c];
        x1[(row0 + r) * 100 + c] = fmaxf(acc, 0.0f);
    }
}

// ---------------- xm = x1 + relu(x@lin1W^T + b1l); z = x1 + relu(x@lin2W^T+b2l)
__global__ __launch_bounds__(256) void k_lin(const float* __restrict__ x,
                                             const float* __restrict__ x1,
                                             const float* __restrict__ W1l,
                                             const float* __restrict__ b1l,
                                             const float* __restrict__ W2l,
                                             const float* __restrict__ b2l,
                                             float* __restrict__ xm,
                                             float* __restrict__ z) {
    __shared__ float Wa[100 * 59];  // stride 59 to break bank conflicts
    __shared__ float Wb[100 * 59];
    __shared__ float Ax[16][58];
    int row0 = blockIdx.x * 16;
    for (int idx = threadIdx.x; idx < 100 * 58; idx += 256) {
        int j = idx / 58, k = idx % 58;
        Wa[j * 59 + k] = W1l[idx];
        Wb[j * 59 + k] = W2l[idx];
    }
    for (int idx = threadIdx.x; idx < 16 * 58; idx += 256)
        Ax[idx / 58][idx % 58] = x[row0 * 58 + idx];
    __syncthreads();
    for (int idx = threadIdx.x; idx < 16 * 100; idx += 256) {
        int r = idx / 100, j = idx % 100;
        float s1 = b1l[j], s2 = b2l[j];
        for (int k = 0; k < 58; k++) {
            float xv = Ax[r][k];
            s1 += xv * Wa[j * 59 + k];
            s2 += xv * Wb[j * 59 + k];
        }
        float xv1 = x1[(row0 + r) * 100 + j];
        xm[(row0 + r) * 100 + j] = xv1 + fmaxf(s1, 0.0f);
        z[(row0 + r) * 100 + j] = xv1 + fmaxf(s2, 0.0f);
    }
}

// ---------------- edge scores + loss partials (pos and neg fused) -------------
#define SCORE_BLOCKS 4096
__global__ __launch_bounds__(256) void k_score(const float* __restrict__ z,
                                               const int* __restrict__ ei,
                                               const int* __restrict__ nei,
                                               double* __restrict__ red) {
    int lane = threadIdx.x & 31;
    int sub = (blockIdx.x * 256 + threadIdx.x) >> 5;
    int nsub = SCORE_BLOCKS * 8;
    double acc = 0.0;
    for (int idx = sub; idx < 2 * NE; idx += nsub) {
        int a, b;
        bool pos;
        if (idx < NE) {
            pos = true;
            a = ei[idx];
            b = ei[NE + idx];
        } else {
            pos = false;
            int e = idx - NE;
            a = nei[e];
            b = nei[NE + e];
        }
        const float* za = z + (size_t)a * 100;
        const float* zb = z + (size_t)b * 100;
        float p = 0.0f;
        for (int k = lane; k < 100; k += 32) p += za[k] * zb[k];
        for (int off = 16; off; off >>= 1) p += __shfl_down(p, off, 32);
        if (lane == 0) {
            float sg = 1.0f / (1.0f + expf(-p));
            float term = pos ? logf(sg + 1e-15f) : logf(1.0f - sg + 1e-15f);
            acc += (double)term;
        }
    }
    __shared__ double sred[256];
    sred[threadIdx.x] = acc;
    __syncthreads();
    for (int s = 128; s; s >>= 1) {
        if (threadIdx.x < s) sred[threadIdx.x] += sred[threadIdx.x + s];
        __syncthreads();
    }
    if (threadIdx.x == 0) red[blockIdx.x] = sred[0];
}

__global__ void k_final(const double* __restrict__ red, const float* __restrict__ c1,
                        const float* __restrict__ c2, float* __restrict__ out) {
    double a = 0.0;
    for (int i = threadIdx.x; i < SCORE_BLOCKS; i += 256) a += red[i];
    __shared__ double sred[256];
    sred[threadIdx.x] = a;
    __syncthreads();
    for (int s = 128; s; s >>= 1) {
        if (threadIdx.x < s) sred[threadIdx.x] += sred[threadIdx.x + s];
        __syncthreads();
    }
    if (threadIdx.x == 0) {
        out[NN] = (float)(-sred[0] / (double)NE);
        out[NN + 1] = c1[0];
        out[NN + 2] = c2[0];
    }
}

// ---------------- layer3: out[n]=xm@W3_0+b3 (pre-scatter), s[n]=xm@W3_1 -------
__global__ __launch_bounds__(256) void k_l3(const float* __restrict__ xm,
                                            const float* __restrict__ W30,
                                            const float* __restrict__ W31,
                                            const float* __restrict__ b3,
                                            float* __restrict__ out,
                                            float* __restrict__ s) {
    int lane = threadIdx.x & 31;
    int n = (blockIdx.x * 256 + threadIdx.x) >> 5;
    if (n >= NN) return;
    const float* row = xm + (size_t)n * 100;
    float d0 = 0.0f, d1 = 0.0f;
    for (int k = lane; k < 100; k += 32) {
        float v = row[k];
        d0 += v * W30[k];
        d1 += v * W31[k];
    }
    for (int off = 16; off; off >>= 1) {
        d0 += __shfl_down(d0, off, 32);
        d1 += __shfl_down(d1, off, 32);
    }
    if (lane == 0) {
        out[n] = d0 + b3[0];
        s[n] = d1;
    }
}

// ---------------- layer3 scatter straight into d_out ----------------
__global__ void k_scat1(const int* __restrict__ ei, const float* __restrict__ s,
                        const float* __restrict__ norm, float* __restrict__ out) {
    int e = blockIdx.x * 256 + threadIdx.x;
    if (e < NE) atomicAdd(&out[ei[NE + e]], norm[e] * s[ei[e]]);
}

extern "C" void kernel_launch(void* const* d_in, const int* in_sizes, int n_in,
                              void* d_out, int out_size, void* d_ws, size_t ws_size,
                              hipStream_t stream) {
    const float* x    = (const float*)d_in[0];
    const int*   ei   = (const int*)d_in[1];
    const int*   nei  = (const int*)d_in[2];
    const float* W1_0 = (const float*)d_in[3];
    const float* W1_1 = (const float*)d_in[4];
    const float* b1   = (const float*)d_in[5];
    const float* W2_0 = (const float*)d_in[6];
    const float* W2_1 = (const float*)d_in[7];
    const float* b2   = (const float*)d_in[8];
    const float* W3_0 = (const float*)d_in[9];
    const float* W3_1 = (const float*)d_in[10];
    const float* b3   = (const float*)d_in[11];
    const float* l1W  = (const float*)d_in[12];
    const float* l1b  = (const float*)d_in[13];
    const float* l2W  = (const float*)d_in[14];
    const float* l2b  = (const float*)d_in[15];
    const float* c1   = (const float*)d_in[16];
    const float* c2   = (const float*)d_in[17];
    float* out = (float*)d_out;
    float* w = (float*)d_ws;

    // workspace layout (floats)
    float*  norm = w;                       // E
    float*  deg  = w + 800000;              // N
    float*  dis  = w + 850000;              // N
    float*  sbuf = w + 900000;              // N
    double* red  = (double*)(w + 1000000);  // 4096 doubles
    float*  base = w + 1008192;
    float* h   = base;                      // 15M   (dead after x1)
    float* tx1 = base + 15000000;           // 2.9M  (dead after h)
    float* hw  = base + 15000000;           // 5M    (overwrites tx1)
    float* tx2 = base + 20000000;           // 5M
    float* x1  = base + 25000000;           // 5M
    float* xm  = base;                      // 5M (reuse h region)
    float* zz  = base + 5000000;            // 5M (reuse h region)

    hipMemsetAsync(deg, 0, NN * sizeof(float), stream);
    hipMemsetAsync(tx1, 0, (size_t)NN * 58 * sizeof(float), stream);
    hipMemsetAsync(tx2, 0, (size_t)NN * 100 * sizeof(float), stream);

    k_deg<<<(NE + 255) / 256, 256, 0, stream>>>(ei, deg);
    k_dis<<<(NN + 255) / 256, 256, 0, stream>>>(deg, dis);
    k_norm<<<(NE + 255) / 256, 256, 0, stream>>>(ei, dis, norm);

    k_scat58<<<(NE * 64) / 256, 256, 0, stream>>>(ei, x, norm, tx1);
    k_gemm1<<<NN / 16, 256, 0, stream>>>(x, tx1, W1_0, W1_1, b1, h);

    k_gemm_hw<<<NN / 16, 256, 0, stream>>>(h, W2_1, hw);
    k_scat100<<<(NE * 128) / 256, 256, 0, stream>>>(ei, hw, norm, tx2);
    k_gemm_x1<<<NN / 16, 256, 0, stream>>>(h, W2_0, tx2, b2, x1);

    k_lin<<<NN / 16, 256, 0, stream>>>(x, x1, l1W, l1b, l2W, l2b, xm, zz);

    k_score<<<SCORE_BLOCKS, 256, 0, stream>>>(zz, ei, nei, red);
    k_final<<<1, 256, 0, stream>>>(red, c1, c2, out);

    k_l3<<<(NN * 32) / 256 + 1, 256, 0, stream>>>(xm, W3_0, W3_1, b3, out, sbuf);
    k_scat1<<<(NE + 255) / 256, 256, 0, stream>>>(ei, sbuf, norm, out);
}

// Round 2
// 1656.265 us; speedup vs baseline: 1.0356x; 1.0356x over previous
//
#include <hip/hip_runtime.h>
#include <math.h>

#define NN 50000
#define NE 800000

// ---------------- degree (over src, for norm) ----------------
__global__ void k_deg(const int* __restrict__ ei, float* __restrict__ deg) {
    int e = blockIdx.x * 256 + threadIdx.x;
    if (e < NE) atomicAdd(&deg[ei[e]], 1.0f);
}

// ---------------- in-degree counts (over dst, for CSR) ----------------
__global__ void k_cnt(const int* __restrict__ ei, int* __restrict__ cnt) {
    int e = blockIdx.x * 256 + threadIdx.x;
    if (e < NE) atomicAdd(&cnt[ei[NE + e]], 1);
}

__global__ void k_dis(const float* __restrict__ deg, float* __restrict__ dis) {
    int i = blockIdx.x * 256 + threadIdx.x;
    if (i < NN) {
        float d = deg[i];
        dis[i] = d > 0.0f ? 1.0f / sqrtf(d) : 0.0f;
    }
}

// ---------------- exclusive scan over cnt -> rowptr (and cursor copy) --------
__global__ __launch_bounds__(256) void k_scan(const int* __restrict__ cnt,
                                              int* __restrict__ rowptr,
                                              int* __restrict__ cursor) {
    __shared__ int sdata[256];
    __shared__ int soff;
    if (threadIdx.x == 0) soff = 0;
    __syncthreads();
    for (int b = 0; b < NN; b += 256) {
        int i = b + threadIdx.x;
        int v = (i < NN) ? cnt[i] : 0;
        sdata[threadIdx.x] = v;
        __syncthreads();
        for (int s = 1; s < 256; s <<= 1) {
            int t = (threadIdx.x >= s) ? sdata[threadIdx.x - s] : 0;
            __syncthreads();
            sdata[threadIdx.x] += t;
            __syncthreads();
        }
        int incl = sdata[threadIdx.x];
        if (i < NN) {
            rowptr[i] = soff + incl - v;
            cursor[i] = soff + incl - v;
        }
        __syncthreads();
        if (threadIdx.x == 0) soff += sdata[255];
        __syncthreads();
    }
    if (threadIdx.x == 0) rowptr[NN] = soff;
}

// ---------------- CSR fill: place (src, norm) per dst ----------------
__global__ void k_fill(const int* __restrict__ ei, const float* __restrict__ dis,
                       int* __restrict__ cursor, int* __restrict__ csrc,
                       float* __restrict__ cnorm) {
    int e = blockIdx.x * 256 + threadIdx.x;
    if (e < NE) {
        int s = ei[e], d = ei[NE + e];
        int p = atomicAdd(&cursor[d], 1);
        csrc[p] = s;
        cnorm[p] = -(dis[s] * dis[d]);
    }
}

// ---------------- layer1 gather: tx1[n,f] = sum_e x[src,f]*cnorm ----------------
__global__ __launch_bounds__(256) void k_gather58(const int* __restrict__ rowptr,
                                                  const int* __restrict__ csrc,
                                                  const float* __restrict__ cnorm,
                                                  const float* __restrict__ x,
                                                  float* __restrict__ tx1) {
    int t = blockIdx.x * 256 + threadIdx.x;
    int n = t >> 6, f = t & 63;
    if (n >= NN) return;
    int beg = rowptr[n], end = rowptr[n + 1];
    if (f < 58) {
        float acc = 0.0f;
        for (int i = beg; i < end; i++)
            acc += x[(size_t)csrc[i] * 58 + f] * cnorm[i];
        tx1[(size_t)n * 58 + f] = acc;
    }
}

// ---------------- layer2 gather: tx2[n,f] = sum_e hw[src,f]*cnorm ----------------
__global__ __launch_bounds__(256) void k_gather100(const int* __restrict__ rowptr,
                                                   const int* __restrict__ csrc,
                                                   const float* __restrict__ cnorm,
                                                   const float* __restrict__ hw,
                                                   float* __restrict__ tx2) {
    int t = blockIdx.x * 256 + threadIdx.x;
    int n = t >> 7, f = t & 127;
    if (n >= NN) return;
    int beg = rowptr[n], end = rowptr[n + 1];
    if (f < 100) {
        float acc = 0.0f;
        for (int i = beg; i < end; i++)
            acc += hw[(size_t)csrc[i] * 100 + f] * cnorm[i];
        tx2[(size_t)n * 100 + f] = acc;
    }
}

// ---------------- h = relu(x@W0 + tx1@W1 + b)  [N,58]->[N,300] ----------------
__global__ __launch_bounds__(256) void k_gemm1(const float* __restrict__ x,
                                               const float* __restrict__ tx1,
                                               const float* __restrict__ W0,
                                               const float* __restrict__ W1,
                                               const float* __restrict__ b,
                                               float* __restrict__ h) {
    __shared__ float Ax[16][58];
    __shared__ float At[16][58];
    int row0 = blockIdx.x * 16;
    for (int idx = threadIdx.x; idx < 16 * 58; idx += 256) {
        Ax[idx / 58][idx % 58] = x[row0 * 58 + idx];
        At[idx / 58][idx % 58] = tx1[row0 * 58 + idx];
    }
    __syncthreads();
    for (int idx = threadIdx.x; idx < 16 * 300; idx += 256) {
        int r = idx / 300, c = idx % 300;
        float acc = b[c];
        for (int k = 0; k < 58; k++)
            acc += Ax[r][k] * W0[k * 300 + c] + At[r][k] * W1[k * 300 + c];
        h[(row0 + r) * 300 + c] = fmaxf(acc, 0.0f);
    }
}

// ---------------- hw = h @ W2_1  [N,300]->[N,100] ----------------
__global__ __launch_bounds__(256) void k_gemm_hw(const float* __restrict__ h,
                                                 const float* __restrict__ W,
                                                 float* __restrict__ hw) {
    __shared__ float Ah[16][300];
    int row0 = blockIdx.x * 16;
    for (int idx = threadIdx.x; idx < 16 * 300; idx += 256)
        Ah[idx / 300][idx % 300] = h[row0 * 300 + idx];
    __syncthreads();
    for (int idx = threadIdx.x; idx < 16 * 100; idx += 256) {
        int r = idx / 100, c = idx % 100;
        float acc = 0.0f;
        for (int k = 0; k < 300; k++) acc += Ah[r][k] * W[k * 100 + c];
        hw[(row0 + r) * 100 + c] = acc;
    }
}

// ---------------- x1 = relu(h@W2_0 + tx2 + b2) ----------------
__global__ __launch_bounds__(256) void k_gemm_x1(const float* __restrict__ h,
                                                 const float* __restrict__ W,
                                                 const float* __restrict__ tx2,
                                                 const float* __restrict__ b,
                                                 float* __restrict__ x1) {
    __shared__ float Ah[16][300];
    int row0 = blockIdx.x * 16;
    for (int idx = threadIdx.x; idx < 16 * 300; idx += 256)
        Ah[idx / 300][idx % 300] = h[row0 * 300 + idx];
    __syncthreads();
    for (int idx = threadIdx.x; idx < 16 * 100; idx += 256) {
        int r = idx / 100, c = idx % 100;
        float acc = b[c];
        for (int k = 0; k < 300; k++) acc += Ah[r][k] * W[k * 100 + c];
        acc += tx2[(row0 + r) * 100 + c];
        x1[(row0 + r) * 100 + c] = fmaxf(acc, 0.0f);
    }
}

// ---------------- xm = x1 + relu(x@lin1W^T + b1l); z = x1 + relu(x@lin2W^T+b2l)
__global__ __launch_bounds__(256) void k_lin(const float* __restrict__ x,
                                             const float* __restrict__ x1,
                                             const float* __restrict__ W1l,
                                             const float* __restrict__ b1l,
                                             const float* __restrict__ W2l,
                                             const float* __restrict__ b2l,
                                             float* __restrict__ xm,
                                             float* __restrict__ z) {
    __shared__ float Wa[100 * 59];
    __shared__ float Wb[100 * 59];
    __shared__ float Ax[16][58];
    int row0 = blockIdx.x * 16;
    for (int idx = threadIdx.x; idx < 100 * 58; idx += 256) {
        int j = idx / 58, k = idx % 58;
        Wa[j * 59 + k] = W1l[idx];
        Wb[j * 59 + k] = W2l[idx];
    }
    for (int idx = threadIdx.x; idx < 16 * 58; idx += 256)
        Ax[idx / 58][idx % 58] = x[row0 * 58 + idx];
    __syncthreads();
    for (int idx = threadIdx.x; idx < 16 * 100; idx += 256) {
        int r = idx / 100, j = idx % 100;
        float s1 = b1l[j], s2 = b2l[j];
        for (int k = 0; k < 58; k++) {
            float xv = Ax[r][k];
            s1 += xv * Wa[j * 59 + k];
            s2 += xv * Wb[j * 59 + k];
        }
        float xv1 = x1[(row0 + r) * 100 + j];
        xm[(row0 + r) * 100 + j] = xv1 + fmaxf(s1, 0.0f);
        z[(row0 + r) * 100 + j] = xv1 + fmaxf(s2, 0.0f);
    }
}

// ---------------- edge scores + loss partials ----------------
#define SCORE_BLOCKS 4096
__global__ __launch_bounds__(256) void k_score(const float* __restrict__ z,
                                               const int* __restrict__ ei,
                                               const int* __restrict__ nei,
                                               double* __restrict__ red) {
    int lane = threadIdx.x & 31;
    int sub = (blockIdx.x * 256 + threadIdx.x) >> 5;
    int nsub = SCORE_BLOCKS * 8;
    double acc = 0.0;
    for (int idx = sub; idx < 2 * NE; idx += nsub) {
        int a, b;
        bool pos;
        if (idx < NE) {
            pos = true;
            a = ei[idx];
            b = ei[NE + idx];
        } else {
            pos = false;
            int e = idx - NE;
            a = nei[e];
            b = nei[NE + e];
        }
        const float* za = z + (size_t)a * 100;
        const float* zb = z + (size_t)b * 100;
        float p = 0.0f;
        for (int k = lane; k < 100; k += 32) p += za[k] * zb[k];
        for (int off = 16; off; off >>= 1) p += __shfl_down(p, off, 32);
        if (lane == 0) {
            float sg = 1.0f / (1.0f + expf(-p));
            float term = pos ? logf(sg + 1e-15f) : logf(1.0f - sg + 1e-15f);
            acc += (double)term;
        }
    }
    __shared__ double sred[256];
    sred[threadIdx.x] = acc;
    __syncthreads();
    for (int s = 128; s; s >>= 1) {
        if (threadIdx.x < s) sred[threadIdx.x] += sred[threadIdx.x + s];
        __syncthreads();
    }
    if (threadIdx.x == 0) red[blockIdx.x] = sred[0];
}

__global__ void k_final(const double* __restrict__ red, const float* __restrict__ c1,
                        const float* __restrict__ c2, float* __restrict__ out) {
    double a = 0.0;
    for (int i = threadIdx.x; i < SCORE_BLOCKS; i += 256) a += red[i];
    __shared__ double sred[256];
    sred[threadIdx.x] = a;
    __syncthreads();
    for (int s = 128; s; s >>= 1) {
        if (threadIdx.x < s) sred[threadIdx.x] += sred[threadIdx.x + s];
        __syncthreads();
    }
    if (threadIdx.x == 0) {
        out[NN] = (float)(-sred[0] / (double)NE);
        out[NN + 1] = c1[0];
        out[NN + 2] = c2[0];
    }
}

// ---------------- layer3: out[n]=xm@W3_0+b3 (pre-gather), s[n]=xm@W3_1 -------
__global__ __launch_bounds__(256) void k_l3(const float* __restrict__ xm,
                                            const float* __restrict__ W30,
                                            const float* __restrict__ W31,
                                            const float* __restrict__ b3,
                                            float* __restrict__ out,
                                            float* __restrict__ s) {
    int lane = threadIdx.x & 31;
    int n = (blockIdx.x * 256 + threadIdx.x) >> 5;
    if (n >= NN) return;
    const float* row = xm + (size_t)n * 100;
    float d0 = 0.0f, d1 = 0.0f;
    for (int k = lane; k < 100; k += 32) {
        float v = row[k];
        d0 += v * W30[k];
        d1 += v * W31[k];
    }
    for (int off = 16; off; off >>= 1) {
        d0 += __shfl_down(d0, off, 32);
        d1 += __shfl_down(d1, off, 32);
    }
    if (lane == 0) {
        out[n] = d0 + b3[0];
        s[n] = d1;
    }
}

// ---------------- layer3 gather: out[n] += sum_e cnorm*s[src] ----------------
__global__ void k_gather1(const int* __restrict__ rowptr, const int* __restrict__ csrc,
                          const float* __restrict__ cnorm, const float* __restrict__ s,
                          float* __restrict__ out) {
    int n = blockIdx.x * 256 + threadIdx.x;
    if (n >= NN) return;
    int beg = rowptr[n], end = rowptr[n + 1];
    float acc = 0.0f;
    for (int i = beg; i < end; i++) acc += cnorm[i] * s[csrc[i]];
    out[n] += acc;
}

extern "C" void kernel_launch(void* const* d_in, const int* in_sizes, int n_in,
                              void* d_out, int out_size, void* d_ws, size_t ws_size,
                              hipStream_t stream) {
    const float* x    = (const float*)d_in[0];
    const int*   ei   = (const int*)d_in[1];
    const int*   nei  = (const int*)d_in[2];
    const float* W1_0 = (const float*)d_in[3];
    const float* W1_1 = (const float*)d_in[4];
    const float* b1   = (const float*)d_in[5];
    const float* W2_0 = (const float*)d_in[6];
    const float* W2_1 = (const float*)d_in[7];
    const float* b2   = (const float*)d_in[8];
    const float* W3_0 = (const float*)d_in[9];
    const float* W3_1 = (const float*)d_in[10];
    const float* b3   = (const float*)d_in[11];
    const float* l1W  = (const float*)d_in[12];
    const float* l1b  = (const float*)d_in[13];
    const float* l2W  = (const float*)d_in[14];
    const float* l2b  = (const float*)d_in[15];
    const float* c1   = (const float*)d_in[16];
    const float* c2   = (const float*)d_in[17];
    float* out = (float*)d_out;
    float* w = (float*)d_ws;

    // workspace layout (float offsets)
    float*  cnorm  = w;                         // 800000
    int*    csrc   = (int*)(w + 800000);        // 800000
    float*  deg    = w + 1600000;               // 50000  [zeroed]
    int*    cnt    = (int*)(w + 1650000);       // 50000  [zeroed]
    float*  dis    = w + 1700000;               // 50000
    int*    rowptr = (int*)(w + 1750000);       // 50001
    int*    cursor = (int*)(w + 1800008);       // 50000
    float*  sbuf   = w + 1850008;               // 50000
    double* red    = (double*)(w + 1900008);    // 4096 doubles = 8192 floats
    float*  base   = w + 1908224;
    float* h   = base;                          // 15M
    float* tx1 = base + 15000000;               // 2.9M (dead after gemm1)
    float* hw  = base + 15000000;               // 5M (overwrites tx1)
    float* tx2 = base + 20000000;               // 5M
    float* x1  = base + 25000000;               // 5M
    float* xm  = base;                          // 5M (reuse h)
    float* zz  = base + 5000000;                // 5M (reuse h)

    hipMemsetAsync(deg, 0, 100000 * sizeof(float), stream);  // deg + cnt contiguous

    k_deg<<<(NE + 255) / 256, 256, 0, stream>>>(ei, deg);
    k_cnt<<<(NE + 255) / 256, 256, 0, stream>>>(ei, cnt);
    k_dis<<<(NN + 255) / 256, 256, 0, stream>>>(deg, dis);
    k_scan<<<1, 256, 0, stream>>>(cnt, rowptr, cursor);
    k_fill<<<(NE + 255) / 256, 256, 0, stream>>>(ei, dis, cursor, csrc, cnorm);

    k_gather58<<<(NN * 64 + 255) / 256, 256, 0, stream>>>(rowptr, csrc, cnorm, x, tx1);
    k_gemm1<<<NN / 16, 256, 0, stream>>>(x, tx1, W1_0, W1_1, b1, h);

    k_gemm_hw<<<NN / 16, 256, 0, stream>>>(h, W2_1, hw);
    k_gather100<<<(NN * 128 + 255) / 256, 256, 0, stream>>>(rowptr, csrc, cnorm, hw, tx2);
    k_gemm_x1<<<NN / 16, 256, 0, stream>>>(h, W2_0, tx2, b2, x1);

    k_lin<<<NN / 16, 256, 0, stream>>>(x, x1, l1W, l1b, l2W, l2b, xm, zz);

    k_score<<<SCORE_BLOCKS, 256, 0, stream>>>(zz, ei, nei, red);
    k_final<<<1, 256, 0, stream>>>(red, c1, c2, out);

    k_l3<<<(NN * 32) / 256 + 1, 256, 0, stream>>>(xm, W3_0, W3_1, b3, out, sbuf);
    k_gather1<<<(NN + 255) / 256, 256, 0, stream>>>(rowptr, csrc, cnorm, sbuf, out);
}

// Round 3
// 667.965 us; speedup vs baseline: 2.5678x; 2.4796x over previous
//
#include <hip/hip_runtime.h>
#include <math.h>

#define NN 50000
#define NE 800000
#define SB 2048

using bf16x8 = __attribute__((ext_vector_type(8))) short;
using f32x4  = __attribute__((ext_vector_type(4))) float;

__device__ __forceinline__ float b2f(short s) {
    union { unsigned u; float f; } v;
    v.u = ((unsigned)(unsigned short)s) << 16;
    return v.f;
}
__device__ __forceinline__ unsigned short f2b(float f) {
    union { float f; unsigned u; } v;
    v.f = f;
    unsigned r = v.u + 0x7fffu + ((v.u >> 16) & 1u);
    return (unsigned short)(r >> 16);
}

// ---------------- degree / counts / dis ----------------
__global__ void k_deg(const int* __restrict__ ei, float* __restrict__ deg) {
    int e = blockIdx.x * 256 + threadIdx.x;
    if (e < NE) atomicAdd(&deg[ei[e]], 1.0f);
}
__global__ void k_cnt(const int* __restrict__ ei, int* __restrict__ cnt) {
    int e = blockIdx.x * 256 + threadIdx.x;
    if (e < NE) atomicAdd(&cnt[ei[NE + e]], 1);
}
__global__ void k_dis(const float* __restrict__ deg, float* __restrict__ dis) {
    int i = blockIdx.x * 256 + threadIdx.x;
    if (i < NN) {
        float d = deg[i];
        dis[i] = d > 0.0f ? 1.0f / sqrtf(d) : 0.0f;
    }
}

// ---------------- chunked exclusive scan (1024 threads, 1 block) -------------
__global__ __launch_bounds__(1024) void k_scan(const int* __restrict__ cnt,
                                               int* __restrict__ rowptr,
                                               int* __restrict__ cursor) {
    __shared__ int ssum[1024];
    int t = threadIdx.x;
    const int CH = 49;  // 1024*49 >= 50000
    int beg = t * CH, end = beg + CH;
    if (end > NN) end = NN;
    int s = 0;
    for (int i = beg; i < end; i++) s += cnt[i];
    ssum[t] = s;
    __syncthreads();
    for (int off = 1; off < 1024; off <<= 1) {
        int v = (t >= off) ? ssum[t - off] : 0;
        __syncthreads();
        ssum[t] += v;
        __syncthreads();
    }
    int run = ssum[t] - s;
    for (int i = beg; i < end; i++) {
        rowptr[i] = run;
        cursor[i] = run;
        run += cnt[i];
    }
    if (t == 1023) rowptr[NN] = ssum[1023];
}

// ---------------- CSR fill ----------------
__global__ void k_fill(const int* __restrict__ ei, const float* __restrict__ dis,
                       int* __restrict__ cursor, int* __restrict__ csrc,
                       float* __restrict__ cnorm) {
    int e = blockIdx.x * 256 + threadIdx.x;
    if (e < NE) {
        int s = ei[e], d = ei[NE + e];
        int p = atomicAdd(&cursor[d], 1);
        csrc[p] = s;
        cnorm[p] = -(dis[s] * dis[d]);
    }
}

// ---------------- x -> bf16 into xcat cols 0..63 ----------------
__global__ void k_conv_x(const float* __restrict__ x, unsigned short* __restrict__ xcat) {
    int t = blockIdx.x * 256 + threadIdx.x;
    int n = t >> 6, k = t & 63;
    float v = (k < 58) ? x[(size_t)n * 58 + k] : 0.0f;
    xcat[(size_t)n * 128 + k] = f2b(v);
}

// ---------------- weight prep (bf16, transposed/padded) ----------------
__global__ void k_prep_w1(const float* __restrict__ W0, const float* __restrict__ W1,
                          unsigned short* __restrict__ Wt1) {
    int t = blockIdx.x * 256 + threadIdx.x;  // 320*128
    int c = t >> 7, k = t & 127;
    float v = 0.0f;
    if (c < 300) {
        if (k < 58) v = W0[k * 300 + c];
        else if (k >= 64 && k < 122) v = W1[(k - 64) * 300 + c];
    }
    Wt1[t] = f2b(v);
}
__global__ void k_prep_w2(const float* __restrict__ W0, const float* __restrict__ W1,
                          unsigned short* __restrict__ Wt2) {
    int j = blockIdx.x, k = threadIdx.x;  // 208 x 320
    float v = 0.0f;
    if (k < 300) {
        if (j < 100) v = W0[k * 100 + j];
        else if (j >= 104 && j < 204) v = W1[k * 100 + (j - 104)];
    }
    Wt2[j * 320 + k] = f2b(v);
}
__global__ void k_prep_wl(const float* __restrict__ L1, const float* __restrict__ L2,
                          unsigned short* __restrict__ Wtl) {
    int j = blockIdx.x, k = threadIdx.x;  // 208 x 64
    float v = 0.0f;
    if (k < 58) {
        if (j < 100) v = L1[j * 58 + k];
        else if (j >= 104 && j < 204) v = L2[(j - 104) * 58 + k];
    }
    Wtl[j * 64 + k] = f2b(v);
}

// ---------------- gather58: xcat cols 64..127 = sum_e cnorm * xb[src] --------
__global__ __launch_bounds__(256) void k_gather58(const int* __restrict__ rowptr,
                                                  const int* __restrict__ csrc,
                                                  const float* __restrict__ cnorm,
                                                  unsigned short* __restrict__ xcat) {
    int t = blockIdx.x * 256 + threadIdx.x;
    int n = t >> 3, l = t & 7;
    if (n >= NN) return;
    int beg = rowptr[n], end = rowptr[n + 1];
    float acc[8] = {0, 0, 0, 0, 0, 0, 0, 0};
    for (int i = beg; i < end; i++) {
        int s = csrc[i];
        float c = cnorm[i];
        bf16x8 v = *(const bf16x8*)(xcat + (size_t)s * 128 + l * 8);
#pragma unroll
        for (int j = 0; j < 8; j++) acc[j] += c * b2f(v[j]);
    }
    bf16x8 o;
#pragma unroll
    for (int j = 0; j < 8; j++) o[j] = (short)f2b(acc[j]);
    *(bf16x8*)(xcat + (size_t)n * 128 + 64 + l * 8) = o;
}

// ---------------- MFMA GEMM 1: h = relu([x|tx1] @ Wt1^T + b1), bf16 out ------
__global__ __launch_bounds__(256) void k_mm1(const unsigned short* __restrict__ xcat,
                                             const unsigned short* __restrict__ Wt1,
                                             const float* __restrict__ b1,
                                             unsigned short* __restrict__ h) {
    int wave = threadIdx.x >> 6, lane = threadIdx.x & 63;
    int row0 = blockIdx.x * 64 + wave * 16;
    if (row0 >= NN) return;
    int ml = lane & 15, quad = lane >> 4;
    const bf16x8* Ap = (const bf16x8*)(xcat + (size_t)(row0 + ml) * 128 + quad * 8);
    bf16x8 a0 = Ap[0], a1 = Ap[4], a2 = Ap[8], a3 = Ap[12];
    for (int nt = 0; nt < 20; nt++) {
        const bf16x8* Bp = (const bf16x8*)(Wt1 + (size_t)(nt * 16 + ml) * 128 + quad * 8);
        f32x4 acc = {0.f, 0.f, 0.f, 0.f};
        acc = __builtin_amdgcn_mfma_f32_16x16x32_bf16(a0, Bp[0], acc, 0, 0, 0);
        acc = __builtin_amdgcn_mfma_f32_16x16x32_bf16(a1, Bp[4], acc, 0, 0, 0);
        acc = __builtin_amdgcn_mfma_f32_16x16x32_bf16(a2, Bp[8], acc, 0, 0, 0);
        acc = __builtin_amdgcn_mfma_f32_16x16x32_bf16(a3, Bp[12], acc, 0, 0, 0);
        int col = nt * 16 + ml;
        float bias = (col < 300) ? b1[col] : 0.0f;
#pragma unroll
        for (int r = 0; r < 4; r++) {
            int row = row0 + quad * 4 + r;
            float v = acc[r] + bias;
            v = v > 0.0f ? v : 0.0f;
            if (col >= 300) v = 0.0f;
            h[(size_t)row * 320 + col] = f2b(v);
        }
    }
}

// ---------------- MFMA GEMM 2: hp = h@W2_0 (fp32), hw = h@W2_1 (bf16) --------
__global__ __launch_bounds__(256) void k_mm2(const unsigned short* __restrict__ h,
                                             const unsigned short* __restrict__ Wt2,
                                             float* __restrict__ hp,
                                             unsigned short* __restrict__ hwb) {
    int wave = threadIdx.x >> 6, lane = threadIdx.x & 63;
    int row0 = blockIdx.x * 64 + wave * 16;
    if (row0 >= NN) return;
    int ml = lane & 15, quad = lane >> 4;
    const bf16x8* Ap = (const bf16x8*)(h + (size_t)(row0 + ml) * 320 + quad * 8);
    bf16x8 a[10];
#pragma unroll
    for (int s = 0; s < 10; s++) a[s] = Ap[s * 4];
    for (int nt = 0; nt < 13; nt++) {
        const bf16x8* Bp = (const bf16x8*)(Wt2 + (size_t)(nt * 16 + ml) * 320 + quad * 8);
        f32x4 acc = {0.f, 0.f, 0.f, 0.f};
#pragma unroll
        for (int s = 0; s < 10; s++)
            acc = __builtin_amdgcn_mfma_f32_16x16x32_bf16(a[s], Bp[s * 4], acc, 0, 0, 0);
        int j = nt * 16 + ml;
#pragma unroll
        for (int r = 0; r < 4; r++) {
            int row = row0 + quad * 4 + r;
            if (j < 104) hp[(size_t)row * 104 + j] = acc[r];
            else hwb[(size_t)row * 104 + (j - 104)] = f2b(acc[r]);
        }
    }
}

// ---------------- gather100: tx2 = sum_e cnorm * hw[src] (fp32 out) ----------
__global__ __launch_bounds__(256) void k_gather100(const int* __restrict__ rowptr,
                                                   const int* __restrict__ csrc,
                                                   const float* __restrict__ cnorm,
                                                   const unsigned short* __restrict__ hwb,
                                                   float* __restrict__ tx2) {
    int t = blockIdx.x * 256 + threadIdx.x;
    int n = t >> 4, l = t & 15;
    if (n >= NN || l >= 13) return;
    int beg = rowptr[n], end = rowptr[n + 1];
    float acc[8] = {0, 0, 0, 0, 0, 0, 0, 0};
    for (int i = beg; i < end; i++) {
        int s = csrc[i];
        float c = cnorm[i];
        bf16x8 v = *(const bf16x8*)(hwb + (size_t)s * 104 + l * 8);
#pragma unroll
        for (int j = 0; j < 8; j++) acc[j] += c * b2f(v[j]);
    }
    f32x4 o0 = {acc[0], acc[1], acc[2], acc[3]};
    f32x4 o1 = {acc[4], acc[5], acc[6], acc[7]};
    *(f32x4*)(tx2 + (size_t)n * 104 + l * 8) = o0;
    *(f32x4*)(tx2 + (size_t)n * 104 + l * 8 + 4) = o1;
}

// ---------------- MFMA lin + fused x1 epilogue -> xm (fp32), z (bf16) --------
__global__ __launch_bounds__(256) void k_mmlin(const unsigned short* __restrict__ xcat,
                                               const unsigned short* __restrict__ Wtl,
                                               const float* __restrict__ hp,
                                               const float* __restrict__ tx2,
                                               const float* __restrict__ b2,
                                               const float* __restrict__ l1b,
                                               const float* __restrict__ l2b,
                                               float* __restrict__ xm,
                                               unsigned short* __restrict__ zb) {
    int wave = threadIdx.x >> 6, lane = threadIdx.x & 63;
    int row0 = blockIdx.x * 64 + wave * 16;
    if (row0 >= NN) return;
    int ml = lane & 15, quad = lane >> 4;
    const bf16x8* Ap = (const bf16x8*)(xcat + (size_t)(row0 + ml) * 128 + quad * 8);
    bf16x8 a0 = Ap[0], a1 = Ap[4];
    for (int nt = 0; nt < 13; nt++) {
        const bf16x8* Bp = (const bf16x8*)(Wtl + (size_t)(nt * 16 + ml) * 64 + quad * 8);
        f32x4 acc = {0.f, 0.f, 0.f, 0.f};
        acc = __builtin_amdgcn_mfma_f32_16x16x32_bf16(a0, Bp[0], acc, 0, 0, 0);
        acc = __builtin_amdgcn_mfma_f32_16x16x32_bf16(a1, Bp[4], acc, 0, 0, 0);
        int j = nt * 16 + ml;
        int jj = (j < 104) ? j : j - 104;
        float bb = 0.0f, lb = 0.0f;
        if (jj < 100) {
            bb = b2[jj];
            lb = (j < 104) ? l1b[jj] : l2b[jj];
        }
#pragma unroll
        for (int r = 0; r < 4; r++) {
            int row = row0 + quad * 4 + r;
            float x1v = hp[(size_t)row * 104 + jj] + tx2[(size_t)row * 104 + jj] + bb;
            x1v = x1v > 0.0f ? x1v : 0.0f;
            float lv = acc[r] + lb;
            lv = lv > 0.0f ? lv : 0.0f;
            float o = x1v + lv;
            if (j < 104) xm[(size_t)row * 104 + j] = o;
            else zb[(size_t)row * 104 + (j - 104)] = f2b(o);
        }
    }
}

// ---------------- edge scores + loss partials (bf16 z) ----------------
__global__ __launch_bounds__(256) void k_score(const unsigned short* __restrict__ zb,
                                               const int* __restrict__ ei,
                                               const int* __restrict__ nei,
                                               double* __restrict__ red) {
    int tid = blockIdx.x * 256 + threadIdx.x;
    int sub = tid >> 4, l = tid & 15;
    int nsub = SB * 16;
    double acc = 0.0;
    for (int idx = sub; idx < 2 * NE; idx += nsub) {
        int a, b;
        if (idx < NE) {
            a = ei[idx];
            b = ei[NE + idx];
        } else {
            int e = idx - NE;
            a = nei[e];
            b = nei[NE + e];
        }
        float p = 0.0f;
        if (l < 13) {
            bf16x8 va = *(const bf16x8*)(zb + (size_t)a * 104 + l * 8);
            bf16x8 vb = *(const bf16x8*)(zb + (size_t)b * 104 + l * 8);
#pragma unroll
            for (int j = 0; j < 8; j++) p += b2f(va[j]) * b2f(vb[j]);
        }
        for (int off = 8; off; off >>= 1) p += __shfl_xor(p, off, 16);
        if (l == 0) {
            float sg = 1.0f / (1.0f + expf(-p));
            float term = (idx < NE) ? logf(sg + 1e-15f) : logf(1.0f - sg + 1e-15f);
            acc += (double)term;
        }
    }
    __shared__ double sred[256];
    sred[threadIdx.x] = acc;
    __syncthreads();
    for (int s = 128; s; s >>= 1) {
        if (threadIdx.x < s) sred[threadIdx.x] += sred[threadIdx.x + s];
        __syncthreads();
    }
    if (threadIdx.x == 0) red[blockIdx.x] = sred[0];
}

__global__ void k_final(const double* __restrict__ red, const float* __restrict__ c1,
                        const float* __restrict__ c2, float* __restrict__ out) {
    double a = 0.0;
    for (int i = threadIdx.x; i < SB; i += 256) a += red[i];
    __shared__ double sred[256];
    sred[threadIdx.x] = a;
    __syncthreads();
    for (int s = 128; s; s >>= 1) {
        if (threadIdx.x < s) sred[threadIdx.x] += sred[threadIdx.x + s];
        __syncthreads();
    }
    if (threadIdx.x == 0) {
        out[NN] = (float)(-sred[0] / (double)NE);
        out[NN + 1] = c1[0];
        out[NN + 2] = c2[0];
    }
}

// ---------------- layer3: out[n]=xm@W3_0+b3, s[n]=xm@W3_1 ----------------
__global__ __launch_bounds__(256) void k_l3(const float* __restrict__ xm,
                                            const float* __restrict__ W30,
                                            const float* __restrict__ W31,
                                            const float* __restrict__ b3,
                                            float* __restrict__ out,
                                            float* __restrict__ s) {
    int lane = threadIdx.x & 31;
    int n = (blockIdx.x * 256 + threadIdx.x) >> 5;
    if (n >= NN) return;
    const float* row = xm + (size_t)n * 104;
    float d0 = 0.0f, d1 = 0.0f;
    for (int k = lane; k < 100; k += 32) {
        float v = row[k];
        d0 += v * W30[k];
        d1 += v * W31[k];
    }
    for (int off = 16; off; off >>= 1) {
        d0 += __shfl_down(d0, off, 32);
        d1 += __shfl_down(d1, off, 32);
    }
    if (lane == 0) {
        out[n] = d0 + b3[0];
        s[n] = d1;
    }
}

__global__ void k_gather1(const int* __restrict__ rowptr, const int* __restrict__ csrc,
                          const float* __restrict__ cnorm, const float* __restrict__ s,
                          float* __restrict__ out) {
    int n = blockIdx.x * 256 + threadIdx.x;
    if (n >= NN) return;
    int beg = rowptr[n], end = rowptr[n + 1];
    float acc = 0.0f;
    for (int i = beg; i < end; i++) acc += cnorm[i] * s[csrc[i]];
    out[n] += acc;
}

extern "C" void kernel_launch(void* const* d_in, const int* in_sizes, int n_in,
                              void* d_out, int out_size, void* d_ws, size_t ws_size,
                              hipStream_t stream) {
    const float* x    = (const float*)d_in[0];
    const int*   ei   = (const int*)d_in[1];
    const int*   nei  = (const int*)d_in[2];
    const float* W1_0 = (const float*)d_in[3];
    const float* W1_1 = (const float*)d_in[4];
    const float* b1   = (const float*)d_in[5];
    const float* W2_0 = (const float*)d_in[6];
    const float* W2_1 = (const float*)d_in[7];
    const float* b2   = (const float*)d_in[8];
    const float* W3_0 = (const float*)d_in[9];
    const float* W3_1 = (const float*)d_in[10];
    const float* b3   = (const float*)d_in[11];
    const float* l1W  = (const float*)d_in[12];
    const float* l1b  = (const float*)d_in[13];
    const float* l2W  = (const float*)d_in[14];
    const float* l2b  = (const float*)d_in[15];
    const float* c1   = (const float*)d_in[16];
    const float* c2   = (const float*)d_in[17];
    float* out = (float*)d_out;
    float* w = (float*)d_ws;

    // workspace (float offsets)
    float*          cnorm  = w;                                   // 800000
    int*            csrc   = (int*)(w + 800000);                  // 800000
    float*          deg    = w + 1600000;                         // 50000 [zeroed]
    int*            cnt    = (int*)(w + 1650000);                 // 50000 [zeroed]
    float*          dis    = w + 1700000;                         // 50000
    int*            rowptr = (int*)(w + 1750000);                 // 50001
    int*            cursor = (int*)(w + 1800008);                 // 50000
    float*          sbuf   = w + 1850008;                         // 50000
    double*         red    = (double*)(w + 1900008);              // 2048 doubles
    unsigned short* xcat   = (unsigned short*)(w + 1908224);      // N*128 bf16 = 3.2M f
    unsigned short* Wt1    = (unsigned short*)(w + 5108224);      // 320*128 bf16
    unsigned short* Wt2    = (unsigned short*)(w + 5128704);      // 208*320 bf16
    unsigned short* Wtl    = (unsigned short*)(w + 5161984);      // 208*64 bf16
    float*          hp     = w + 5168640;                         // N*104 f
    unsigned short* hwb    = (unsigned short*)(w + 10368640);     // N*104 bf16
    float*          xm     = w + 12968640;                        // N*104 f
    unsigned short* zb     = (unsigned short*)(w + 18168640);     // N*104 bf16
    unsigned short* h      = (unsigned short*)(w + 20768640);     // N*320 bf16 = 8M f
    float*          tx2    = w + 20768640;                        // N*104 f (overlays h; h dead)

    hipMemsetAsync(deg, 0, 100000 * sizeof(float), stream);  // deg + cnt contiguous

    // CSR build
    k_deg<<<(NE + 255) / 256, 256, 0, stream>>>(ei, deg);
    k_cnt<<<(NE + 255) / 256, 256, 0, stream>>>(ei, cnt);
    k_dis<<<(NN + 255) / 256, 256, 0, stream>>>(deg, dis);
    k_scan<<<1, 1024, 0, stream>>>(cnt, rowptr, cursor);
    k_fill<<<(NE + 255) / 256, 256, 0, stream>>>(ei, dis, cursor, csrc, cnorm);

    // prep
    k_conv_x<<<NN * 64 / 256, 256, 0, stream>>>(x, xcat);
    k_prep_w1<<<160, 256, 0, stream>>>(W1_0, W1_1, Wt1);
    k_prep_w2<<<208, 320, 0, stream>>>(W2_0, W2_1, Wt2);
    k_prep_wl<<<208, 64, 0, stream>>>(l1W, l2W, Wtl);

    // layer 1
    k_gather58<<<(NN * 8 + 255) / 256, 256, 0, stream>>>(rowptr, csrc, cnorm, xcat);
    k_mm1<<<(NN + 63) / 64, 256, 0, stream>>>(xcat, Wt1, b1, h);

    // layer 2
    k_mm2<<<(NN + 63) / 64, 256, 0, stream>>>(h, Wt2, hp, hwb);
    k_gather100<<<NN * 16 / 256, 256, 0, stream>>>(rowptr, csrc, cnorm, hwb, tx2);

    // lin heads + x1 fusion
    k_mmlin<<<(NN + 63) / 64, 256, 0, stream>>>(xcat, Wtl, hp, tx2, b2, l1b, l2b, xm, zb);

    // loss
    k_score<<<SB, 256, 0, stream>>>(zb, ei, nei, red);
    k_final<<<1, 256, 0, stream>>>(red, c1, c2, out);

    // layer 3
    k_l3<<<NN * 32 / 256, 256, 0, stream>>>(xm, W3_0, W3_1, b3, out, sbuf);
    k_gather1<<<(NN + 255) / 256, 256, 0, stream>>>(rowptr, csrc, cnorm, sbuf, out);
}

// Round 4
// 558.186 us; speedup vs baseline: 3.0729x; 1.1967x over previous
//
#include <hip/hip_runtime.h>
#include <math.h>

#define NN 50000
#define NE 800000
#define SB 2048
#define NB 196  // ceil(NN/256)

using bf16x8 = __attribute__((ext_vector_type(8))) short;
using f32x4  = __attribute__((ext_vector_type(4))) float;

__device__ __forceinline__ float b2f(short s) {
    union { unsigned u; float f; } v;
    v.u = ((unsigned)(unsigned short)s) << 16;
    return v.f;
}
__device__ __forceinline__ unsigned short f2b(float f) {
    union { float f; unsigned u; } v;
    v.f = f;
    unsigned r = v.u + 0x7fffu + ((v.u >> 16) & 1u);
    return (unsigned short)(r >> 16);
}

// ---------------- fused degree counts: src (for norm) + dst (for CSR) --------
__global__ void k_counts(const int* __restrict__ ei, int* __restrict__ degs,
                         int* __restrict__ cnt) {
    int e = blockIdx.x * 256 + threadIdx.x;
    if (e < NE) {
        atomicAdd(&degs[ei[e]], 1);
        atomicAdd(&cnt[ei[NE + e]], 1);
    }
}

__global__ void k_dis(const int* __restrict__ degs, float* __restrict__ dis) {
    int i = blockIdx.x * 256 + threadIdx.x;
    if (i < NN) {
        float d = (float)degs[i];
        dis[i] = d > 0.0f ? 1.0f / sqrtf(d) : 0.0f;
    }
}

// ---------------- 3-phase scan ----------------
__global__ __launch_bounds__(256) void k_scan1(const int* __restrict__ cnt,
                                               int* __restrict__ rowptr,
                                               int* __restrict__ bsum) {
    __shared__ int sdata[256];
    int i = blockIdx.x * 256 + threadIdx.x;
    int v = (i < NN) ? cnt[i] : 0;
    sdata[threadIdx.x] = v;
    __syncthreads();
    for (int s = 1; s < 256; s <<= 1) {
        int t = (threadIdx.x >= s) ? sdata[threadIdx.x - s] : 0;
        __syncthreads();
        sdata[threadIdx.x] += t;
        __syncthreads();
    }
    if (i < NN) rowptr[i] = sdata[threadIdx.x] - v;
    if (threadIdx.x == 255) bsum[blockIdx.x] = sdata[255];
}

__global__ __launch_bounds__(256) void k_scan2(int* __restrict__ bsum,
                                               int* __restrict__ rowptr) {
    __shared__ int sdata[256];
    int t = threadIdx.x;
    int v = (t < NB) ? bsum[t] : 0;
    sdata[t] = v;
    __syncthreads();
    for (int s = 1; s < 256; s <<= 1) {
        int x = (t >= s) ? sdata[t - s] : 0;
        __syncthreads();
        sdata[t] += x;
        __syncthreads();
    }
    if (t < NB) bsum[t] = sdata[t] - v;  // exclusive
    if (t == 255) rowptr[NN] = sdata[255];
}

__global__ __launch_bounds__(256) void k_scan3(const int* __restrict__ bsum,
                                               int* __restrict__ rowptr,
                                               int* __restrict__ cursor) {
    int i = blockIdx.x * 256 + threadIdx.x;
    if (i < NN) {
        int r = rowptr[i] + bsum[blockIdx.x];
        rowptr[i] = r;
        cursor[i] = r;
    }
}

// ---------------- CSR fill ----------------
__global__ void k_fill(const int* __restrict__ ei, const float* __restrict__ dis,
                       int* __restrict__ cursor, int* __restrict__ csrc,
                       float* __restrict__ cnorm) {
    int e = blockIdx.x * 256 + threadIdx.x;
    if (e < NE) {
        int s = ei[e], d = ei[NE + e];
        int p = atomicAdd(&cursor[d], 1);
        csrc[p] = s;
        cnorm[p] = -(dis[s] * dis[d]);
    }
}

// ---------------- x -> bf16 into xcat cols 0..63 ----------------
__global__ void k_conv_x(const float* __restrict__ x, unsigned short* __restrict__ xcat) {
    int t = blockIdx.x * 256 + threadIdx.x;
    int n = t >> 6, k = t & 63;
    float v = (k < 58) ? x[(size_t)n * 58 + k] : 0.0f;
    xcat[(size_t)n * 128 + k] = f2b(v);
}

// ---------------- weight prep (bf16, transposed/padded) ----------------
__global__ void k_prep_w1(const float* __restrict__ W0, const float* __restrict__ W1,
                          unsigned short* __restrict__ Wt1) {
    int t = blockIdx.x * 256 + threadIdx.x;  // 320*128
    int c = t >> 7, k = t & 127;
    float v = 0.0f;
    if (c < 300) {
        if (k < 58) v = W0[k * 300 + c];
        else if (k >= 64 && k < 122) v = W1[(k - 64) * 300 + c];
    }
    Wt1[t] = f2b(v);
}
__global__ void k_prep_w2(const float* __restrict__ W0, const float* __restrict__ W1,
                          unsigned short* __restrict__ Wt2) {
    int j = blockIdx.x, k = threadIdx.x;  // 208 x 320
    float v = 0.0f;
    if (k < 300) {
        if (j < 100) v = W0[k * 100 + j];
        else if (j >= 104 && j < 204) v = W1[k * 100 + (j - 104)];
    }
    Wt2[j * 320 + k] = f2b(v);
}
__global__ void k_prep_wl(const float* __restrict__ L1, const float* __restrict__ L2,
                          unsigned short* __restrict__ Wtl) {
    int j = blockIdx.x, k = threadIdx.x;  // 208 x 64
    float v = 0.0f;
    if (k < 58) {
        if (j < 100) v = L1[j * 58 + k];
        else if (j >= 104 && j < 204) v = L2[(j - 104) * 58 + k];
    }
    Wtl[j * 64 + k] = f2b(v);
}

// ---------------- gather58: xcat cols 64..127 = sum_e cnorm * xb[src] --------
__global__ __launch_bounds__(256) void k_gather58(const int* __restrict__ rowptr,
                                                  const int* __restrict__ csrc,
                                                  const float* __restrict__ cnorm,
                                                  unsigned short* __restrict__ xcat) {
    int t = blockIdx.x * 256 + threadIdx.x;
    int n = t >> 3, l = t & 7;
    if (n >= NN) return;
    int beg = rowptr[n], end = rowptr[n + 1];
    float acc[8] = {0, 0, 0, 0, 0, 0, 0, 0};
    for (int i = beg; i < end; i++) {
        int s = csrc[i];
        float c = cnorm[i];
        bf16x8 v = *(const bf16x8*)(xcat + (size_t)s * 128 + l * 8);
#pragma unroll
        for (int j = 0; j < 8; j++) acc[j] += c * b2f(v[j]);
    }
    bf16x8 o;
#pragma unroll
    for (int j = 0; j < 8; j++) o[j] = (short)f2b(acc[j]);
    *(bf16x8*)(xcat + (size_t)n * 128 + 64 + l * 8) = o;
}

// ---------------- MFMA GEMM 1: h = relu([x|tx1] @ Wt1^T + b1), bf16 out ------
__global__ __launch_bounds__(256) void k_mm1(const unsigned short* __restrict__ xcat,
                                             const unsigned short* __restrict__ Wt1,
                                             const float* __restrict__ b1,
                                             unsigned short* __restrict__ h) {
    int wave = threadIdx.x >> 6, lane = threadIdx.x & 63;
    int row0 = blockIdx.x * 64 + wave * 16;
    if (row0 >= NN) return;
    int ml = lane & 15, quad = lane >> 4;
    const bf16x8* Ap = (const bf16x8*)(xcat + (size_t)(row0 + ml) * 128 + quad * 8);
    bf16x8 a0 = Ap[0], a1 = Ap[4], a2 = Ap[8], a3 = Ap[12];
    for (int nt = 0; nt < 20; nt++) {
        const bf16x8* Bp = (const bf16x8*)(Wt1 + (size_t)(nt * 16 + ml) * 128 + quad * 8);
        f32x4 acc = {0.f, 0.f, 0.f, 0.f};
        acc = __builtin_amdgcn_mfma_f32_16x16x32_bf16(a0, Bp[0], acc, 0, 0, 0);
        acc = __builtin_amdgcn_mfma_f32_16x16x32_bf16(a1, Bp[4], acc, 0, 0, 0);
        acc = __builtin_amdgcn_mfma_f32_16x16x32_bf16(a2, Bp[8], acc, 0, 0, 0);
        acc = __builtin_amdgcn_mfma_f32_16x16x32_bf16(a3, Bp[12], acc, 0, 0, 0);
        int col = nt * 16 + ml;
        float bias = (col < 300) ? b1[col] : 0.0f;
#pragma unroll
        for (int r = 0; r < 4; r++) {
            int row = row0 + quad * 4 + r;
            float v = acc[r] + bias;
            v = v > 0.0f ? v : 0.0f;
            if (col >= 300) v = 0.0f;
            h[(size_t)row * 320 + col] = f2b(v);
        }
    }
}

// ---------------- MFMA GEMM 2: hp = h@W2_0 (fp32), hw = h@W2_1 (bf16) --------
__global__ __launch_bounds__(256) void k_mm2(const unsigned short* __restrict__ h,
                                             const unsigned short* __restrict__ Wt2,
                                             float* __restrict__ hp,
                                             unsigned short* __restrict__ hwb) {
    int wave = threadIdx.x >> 6, lane = threadIdx.x & 63;
    int row0 = blockIdx.x * 64 + wave * 16;
    if (row0 >= NN) return;
    int ml = lane & 15, quad = lane >> 4;
    const bf16x8* Ap = (const bf16x8*)(h + (size_t)(row0 + ml) * 320 + quad * 8);
    bf16x8 a[10];
#pragma unroll
    for (int s = 0; s < 10; s++) a[s] = Ap[s * 4];
    for (int nt = 0; nt < 13; nt++) {
        const bf16x8* Bp = (const bf16x8*)(Wt2 + (size_t)(nt * 16 + ml) * 320 + quad * 8);
        f32x4 acc = {0.f, 0.f, 0.f, 0.f};
#pragma unroll
        for (int s = 0; s < 10; s++)
            acc = __builtin_amdgcn_mfma_f32_16x16x32_bf16(a[s], Bp[s * 4], acc, 0, 0, 0);
        int j = nt * 16 + ml;
#pragma unroll
        for (int r = 0; r < 4; r++) {
            int row = row0 + quad * 4 + r;
            if (j < 104) hp[(size_t)row * 104 + j] = acc[r];
            else hwb[(size_t)row * 104 + (j - 104)] = f2b(acc[r]);
        }
    }
}

// ---------------- gather100: tx2 = sum_e cnorm * hw[src] (fp32 out) ----------
__global__ __launch_bounds__(256) void k_gather100(const int* __restrict__ rowptr,
                                                   const int* __restrict__ csrc,
                                                   const float* __restrict__ cnorm,
                                                   const unsigned short* __restrict__ hwb,
                                                   float* __restrict__ tx2) {
    int t = blockIdx.x * 256 + threadIdx.x;
    int n = t >> 4, l = t & 15;
    if (n >= NN || l >= 13) return;
    int beg = rowptr[n], end = rowptr[n + 1];
    float acc[8] = {0, 0, 0, 0, 0, 0, 0, 0};
    for (int i = beg; i < end; i++) {
        int s = csrc[i];
        float c = cnorm[i];
        bf16x8 v = *(const bf16x8*)(hwb + (size_t)s * 104 + l * 8);
#pragma unroll
        for (int j = 0; j < 8; j++) acc[j] += c * b2f(v[j]);
    }
    f32x4 o0 = {acc[0], acc[1], acc[2], acc[3]};
    f32x4 o1 = {acc[4], acc[5], acc[6], acc[7]};
    *(f32x4*)(tx2 + (size_t)n * 104 + l * 8) = o0;
    *(f32x4*)(tx2 + (size_t)n * 104 + l * 8 + 4) = o1;
}

// ---------------- MFMA lin + fused x1 epilogue -> xm (fp32), z (bf16) --------
__global__ __launch_bounds__(256) void k_mmlin(const unsigned short* __restrict__ xcat,
                                               const unsigned short* __restrict__ Wtl,
                                               const float* __restrict__ hp,
                                               const float* __restrict__ tx2,
                                               const float* __restrict__ b2,
                                               const float* __restrict__ l1b,
                                               const float* __restrict__ l2b,
                                               float* __restrict__ xm,
                                               unsigned short* __restrict__ zb) {
    int wave = threadIdx.x >> 6, lane = threadIdx.x & 63;
    int row0 = blockIdx.x * 64 + wave * 16;
    if (row0 >= NN) return;
    int ml = lane & 15, quad = lane >> 4;
    const bf16x8* Ap = (const bf16x8*)(xcat + (size_t)(row0 + ml) * 128 + quad * 8);
    bf16x8 a0 = Ap[0], a1 = Ap[4];
    for (int nt = 0; nt < 13; nt++) {
        const bf16x8* Bp = (const bf16x8*)(Wtl + (size_t)(nt * 16 + ml) * 64 + quad * 8);
        f32x4 acc = {0.f, 0.f, 0.f, 0.f};
        acc = __builtin_amdgcn_mfma_f32_16x16x32_bf16(a0, Bp[0], acc, 0, 0, 0);
        acc = __builtin_amdgcn_mfma_f32_16x16x32_bf16(a1, Bp[4], acc, 0, 0, 0);
        int j = nt * 16 + ml;
        int jj = (j < 104) ? j : j - 104;
        float bb = 0.0f, lb = 0.0f;
        if (jj < 100) {
            bb = b2[jj];
            lb = (j < 104) ? l1b[jj] : l2b[jj];
        }
#pragma unroll
        for (int r = 0; r < 4; r++) {
            int row = row0 + quad * 4 + r;
            float x1v = hp[(size_t)row * 104 + jj] + tx2[(size_t)row * 104 + jj] + bb;
            x1v = x1v > 0.0f ? x1v : 0.0f;
            float lv = acc[r] + lb;
            lv = lv > 0.0f ? lv : 0.0f;
            float o = x1v + lv;
            if (j < 104) xm[(size_t)row * 104 + j] = o;
            else zb[(size_t)row * 104 + (j - 104)] = f2b(o);
        }
    }
}

// ---------------- edge scores + loss partials (bf16 z) ----------------
__global__ __launch_bounds__(256) void k_score(const unsigned short* __restrict__ zb,
                                               const int* __restrict__ ei,
                                               const int* __restrict__ nei,
                                               double* __restrict__ red) {
    int tid = blockIdx.x * 256 + threadIdx.x;
    int sub = tid >> 4, l = tid & 15;
    int nsub = SB * 16;
    double acc = 0.0;
    for (int idx = sub; idx < 2 * NE; idx += nsub) {
        int a, b;
        if (idx < NE) {
            a = ei[idx];
            b = ei[NE + idx];
        } else {
            int e = idx - NE;
            a = nei[e];
            b = nei[NE + e];
        }
        float p = 0.0f;
        if (l < 13) {
            bf16x8 va = *(const bf16x8*)(zb + (size_t)a * 104 + l * 8);
            bf16x8 vb = *(const bf16x8*)(zb + (size_t)b * 104 + l * 8);
#pragma unroll
            for (int j = 0; j < 8; j++) p += b2f(va[j]) * b2f(vb[j]);
        }
        for (int off = 8; off; off >>= 1) p += __shfl_xor(p, off, 16);
        if (l == 0) {
            float sg = 1.0f / (1.0f + expf(-p));
            float term = (idx < NE) ? logf(sg + 1e-15f) : logf(1.0f - sg + 1e-15f);
            acc += (double)term;
        }
    }
    __shared__ double sred[256];
    sred[threadIdx.x] = acc;
    __syncthreads();
    for (int s = 128; s; s >>= 1) {
        if (threadIdx.x < s) sred[threadIdx.x] += sred[threadIdx.x + s];
        __syncthreads();
    }
    if (threadIdx.x == 0) red[blockIdx.x] = sred[0];
}

__global__ void k_final(const double* __restrict__ red, const float* __restrict__ c1,
                        const float* __restrict__ c2, float* __restrict__ out) {
    double a = 0.0;
    for (int i = threadIdx.x; i < SB; i += 256) a += red[i];
    __shared__ double sred[256];
    sred[threadIdx.x] = a;
    __syncthreads();
    for (int s = 128; s; s >>= 1) {
        if (threadIdx.x < s) sred[threadIdx.x] += sred[threadIdx.x + s];
        __syncthreads();
    }
    if (threadIdx.x == 0) {
        out[NN] = (float)(-sred[0] / (double)NE);
        out[NN + 1] = c1[0];
        out[NN + 2] = c2[0];
    }
}

// ---------------- layer3: out[n]=xm@W3_0+b3, s[n]=xm@W3_1 ----------------
__global__ __launch_bounds__(256) void k_l3(const float* __restrict__ xm,
                                            const float* __restrict__ W30,
                                            const float* __restrict__ W31,
                                            const float* __restrict__ b3,
                                            float* __restrict__ out,
                                            float* __restrict__ s) {
    int lane = threadIdx.x & 31;
    int n = (blockIdx.x * 256 + threadIdx.x) >> 5;
    if (n >= NN) return;
    const float* row = xm + (size_t)n * 104;
    float d0 = 0.0f, d1 = 0.0f;
    for (int k = lane; k < 100; k += 32) {
        float v = row[k];
        d0 += v * W30[k];
        d1 += v * W31[k];
    }
    for (int off = 16; off; off >>= 1) {
        d0 += __shfl_down(d0, off, 32);
        d1 += __shfl_down(d1, off, 32);
    }
    if (lane == 0) {
        out[n] = d0 + b3[0];
        s[n] = d1;
    }
}

__global__ void k_gather1(const int* __restrict__ rowptr, const int* __restrict__ csrc,
                          const float* __restrict__ cnorm, const float* __restrict__ s,
                          float* __restrict__ out) {
    int n = blockIdx.x * 256 + threadIdx.x;
    if (n >= NN) return;
    int beg = rowptr[n], end = rowptr[n + 1];
    float acc = 0.0f;
    for (int i = beg; i < end; i++) acc += cnorm[i] * s[csrc[i]];
    out[n] += acc;
}

extern "C" void kernel_launch(void* const* d_in, const int* in_sizes, int n_in,
                              void* d_out, int out_size, void* d_ws, size_t ws_size,
                              hipStream_t stream) {
    const float* x    = (const float*)d_in[0];
    const int*   ei   = (const int*)d_in[1];
    const int*   nei  = (const int*)d_in[2];
    const float* W1_0 = (const float*)d_in[3];
    const float* W1_1 = (const float*)d_in[4];
    const float* b1   = (const float*)d_in[5];
    const float* W2_0 = (const float*)d_in[6];
    const float* W2_1 = (const float*)d_in[7];
    const float* b2   = (const float*)d_in[8];
    const float* W3_0 = (const float*)d_in[9];
    const float* W3_1 = (const float*)d_in[10];
    const float* b3   = (const float*)d_in[11];
    const float* l1W  = (const float*)d_in[12];
    const float* l1b  = (const float*)d_in[13];
    const float* l2W  = (const float*)d_in[14];
    const float* l2b  = (const float*)d_in[15];
    const float* c1   = (const float*)d_in[16];
    const float* c2   = (const float*)d_in[17];
    float* out = (float*)d_out;
    float* w = (float*)d_ws;

    // workspace (float offsets)
    float*          cnorm  = w;                                   // 800000
    int*            csrc   = (int*)(w + 800000);                  // 800000
    int*            degs   = (int*)(w + 1600000);                 // 50000 [zeroed]
    int*            cnt    = (int*)(w + 1650000);                 // 50000 [zeroed]
    float*          dis    = w + 1700000;                         // 50000
    int*            rowptr = (int*)(w + 1750000);                 // 50001
    int*            cursor = (int*)(w + 1800008);                 // 50000
    float*          sbuf   = w + 1850008;                         // 50000
    int*            bsum   = (int*)(w + 1900008);                 // 256
    double*         red    = (double*)(w + 1900520);              // 2048 doubles
    unsigned short* xcat   = (unsigned short*)(w + 1908736);      // N*128 bf16
    unsigned short* Wt1    = (unsigned short*)(w + 5108736);      // 320*128 bf16
    unsigned short* Wt2    = (unsigned short*)(w + 5129216);      // 208*320 bf16
    unsigned short* Wtl    = (unsigned short*)(w + 5162496);      // 208*64 bf16
    float*          hp     = w + 5169152;                         // N*104 f
    unsigned short* hwb    = (unsigned short*)(w + 10369152);     // N*104 bf16
    float*          xm     = w + 12969152;                        // N*104 f
    unsigned short* zb     = (unsigned short*)(w + 18169152);     // N*104 bf16
    unsigned short* h      = (unsigned short*)(w + 20769152);     // N*320 bf16
    float*          tx2    = w + 20769152;                        // N*104 f (overlays h)

    hipMemsetAsync(degs, 0, 100000 * sizeof(int), stream);  // degs + cnt contiguous

    // CSR build
    k_counts<<<(NE + 255) / 256, 256, 0, stream>>>(ei, degs, cnt);
    k_dis<<<(NN + 255) / 256, 256, 0, stream>>>(degs, dis);
    k_scan1<<<NB, 256, 0, stream>>>(cnt, rowptr, bsum);
    k_scan2<<<1, 256, 0, stream>>>(bsum, rowptr);
    k_scan3<<<NB, 256, 0, stream>>>(bsum, rowptr, cursor);
    k_fill<<<(NE + 255) / 256, 256, 0, stream>>>(ei, dis, cursor, csrc, cnorm);

    // prep
    k_conv_x<<<NN * 64 / 256, 256, 0, stream>>>(x, xcat);
    k_prep_w1<<<160, 256, 0, stream>>>(W1_0, W1_1, Wt1);
    k_prep_w2<<<208, 320, 0, stream>>>(W2_0, W2_1, Wt2);
    k_prep_wl<<<208, 64, 0, stream>>>(l1W, l2W, Wtl);

    // layer 1
    k_gather58<<<(NN * 8 + 255) / 256, 256, 0, stream>>>(rowptr, csrc, cnorm, xcat);
    k_mm1<<<(NN + 63) / 64, 256, 0, stream>>>(xcat, Wt1, b1, h);

    // layer 2
    k_mm2<<<(NN + 63) / 64, 256, 0, stream>>>(h, Wt2, hp, hwb);
    k_gather100<<<NN * 16 / 256, 256, 0, stream>>>(rowptr, csrc, cnorm, hwb, tx2);

    // lin heads + x1 fusion
    k_mmlin<<<(NN + 63) / 64, 256, 0, stream>>>(xcat, Wtl, hp, tx2, b2, l1b, l2b, xm, zb);

    // loss
    k_score<<<SB, 256, 0, stream>>>(zb, ei, nei, red);
    k_final<<<1, 256, 0, stream>>>(red, c1, c2, out);

    // layer 3
    k_l3<<<NN * 32 / 256, 256, 0, stream>>>(xm, W3_0, W3_1, b3, out, sbuf);
    k_gather1<<<(NN + 255) / 256, 256, 0, stream>>>(rowptr, csrc, cnorm, sbuf, out);
}

// Round 5
// 512.290 us; speedup vs baseline: 3.3482x; 1.0896x over previous
//
#include <hip/hip_runtime.h>
#include <math.h>

#define NN 50000
#define NE 800000
#define SB 2048
#define NB 196  // ceil(NN/256)

using bf16x8 = __attribute__((ext_vector_type(8))) short;
using f32x4  = __attribute__((ext_vector_type(4))) float;
using f32x2  = __attribute__((ext_vector_type(2))) float;

__device__ __forceinline__ float b2f(short s) {
    union { unsigned u; float f; } v;
    v.u = ((unsigned)(unsigned short)s) << 16;
    return v.f;
}
__device__ __forceinline__ unsigned short f2b(float f) {
    union { float f; unsigned u; } v;
    v.f = f;
    unsigned r = v.u + 0x7fffu + ((v.u >> 16) & 1u);
    return (unsigned short)(r >> 16);
}
__device__ __forceinline__ unsigned char f2e4m3(float f) {
    return (unsigned char)(__builtin_amdgcn_cvt_pk_fp8_f32(f, f, 0, false) & 0xff);
}

// ---------------- fused degree counts ----------------
__global__ void k_counts(const int* __restrict__ ei, int* __restrict__ degs,
                         int* __restrict__ cnt) {
    int e = blockIdx.x * 256 + threadIdx.x;
    if (e < NE) {
        atomicAdd(&degs[ei[e]], 1);
        atomicAdd(&cnt[ei[NE + e]], 1);
    }
}

__global__ void k_dis(const int* __restrict__ degs, float* __restrict__ dis) {
    int i = blockIdx.x * 256 + threadIdx.x;
    if (i < NN) {
        float d = (float)degs[i];
        dis[i] = d > 0.0f ? 1.0f / sqrtf(d) : 0.0f;
    }
}

// ---------------- 3-phase scan ----------------
__global__ __launch_bounds__(256) void k_scan1(const int* __restrict__ cnt,
                                               int* __restrict__ rowptr,
                                               int* __restrict__ bsum) {
    __shared__ int sdata[256];
    int i = blockIdx.x * 256 + threadIdx.x;
    int v = (i < NN) ? cnt[i] : 0;
    sdata[threadIdx.x] = v;
    __syncthreads();
    for (int s = 1; s < 256; s <<= 1) {
        int t = (threadIdx.x >= s) ? sdata[threadIdx.x - s] : 0;
        __syncthreads();
        sdata[threadIdx.x] += t;
        __syncthreads();
    }
    if (i < NN) rowptr[i] = sdata[threadIdx.x] - v;
    if (threadIdx.x == 255) bsum[blockIdx.x] = sdata[255];
}

__global__ __launch_bounds__(256) void k_scan2(int* __restrict__ bsum,
                                               int* __restrict__ rowptr) {
    __shared__ int sdata[256];
    int t = threadIdx.x;
    int v = (t < NB) ? bsum[t] : 0;
    sdata[t] = v;
    __syncthreads();
    for (int s = 1; s < 256; s <<= 1) {
        int x = (t >= s) ? sdata[t - s] : 0;
        __syncthreads();
        sdata[t] += x;
        __syncthreads();
    }
    if (t < NB) bsum[t] = sdata[t] - v;
    if (t == 255) rowptr[NN] = sdata[255];
}

__global__ __launch_bounds__(256) void k_scan3(const int* __restrict__ bsum,
                                               int* __restrict__ rowptr,
                                               int* __restrict__ cursor) {
    int i = blockIdx.x * 256 + threadIdx.x;
    if (i < NN) {
        int r = rowptr[i] + bsum[blockIdx.x];
        rowptr[i] = r;
        cursor[i] = r;
    }
}

// ---------------- CSR fill: packed {src, norm} ----------------
__global__ void k_fill(const int* __restrict__ ei, const float* __restrict__ dis,
                       int* __restrict__ cursor, uint2* __restrict__ cedge) {
    int e = blockIdx.x * 256 + threadIdx.x;
    if (e < NE) {
        int s = ei[e], d = ei[NE + e];
        int p = atomicAdd(&cursor[d], 1);
        uint2 v;
        v.x = (unsigned)s;
        v.y = __float_as_uint(-(dis[s] * dis[d]));
        cedge[p] = v;
    }
}

// ---------------- x -> bf16 (xcat cols 0..63) + fp8 copy (xf8) ----------------
__global__ void k_conv_x(const float* __restrict__ x, unsigned short* __restrict__ xcat,
                         unsigned char* __restrict__ xf8) {
    int t = blockIdx.x * 256 + threadIdx.x;
    int n = t >> 6, k = t & 63;
    float v = (k < 58) ? x[(size_t)n * 58 + k] : 0.0f;
    xcat[(size_t)n * 128 + k] = f2b(v);
    xf8[(size_t)n * 64 + k] = f2e4m3(v);
}

// ---------------- weight prep (bf16, transposed/padded) ----------------
__global__ void k_prep_w1(const float* __restrict__ W0, const float* __restrict__ W1,
                          unsigned short* __restrict__ Wt1) {
    int t = blockIdx.x * 256 + threadIdx.x;  // 320*128
    int c = t >> 7, k = t & 127;
    float v = 0.0f;
    if (c < 300) {
        if (k < 58) v = W0[k * 300 + c];
        else if (k >= 64 && k < 122) v = W1[(k - 64) * 300 + c];
    }
    Wt1[t] = f2b(v);
}
__global__ void k_prep_w2(const float* __restrict__ W0, const float* __restrict__ W1,
                          unsigned short* __restrict__ Wt2) {
    int j = blockIdx.x, k = threadIdx.x;  // 208 x 320
    float v = 0.0f;
    if (k < 300) {
        if (j < 100) v = W0[k * 100 + j];
        else if (j >= 104 && j < 204) v = W1[k * 100 + (j - 104)];
    }
    Wt2[j * 320 + k] = f2b(v);
}
__global__ void k_prep_wl(const float* __restrict__ L1, const float* __restrict__ L2,
                          unsigned short* __restrict__ Wtl) {
    int j = blockIdx.x, k = threadIdx.x;  // 208 x 64
    float v = 0.0f;
    if (k < 58) {
        if (j < 100) v = L1[j * 58 + k];
        else if (j >= 104 && j < 204) v = L2[(j - 104) * 58 + k];
    }
    Wtl[j * 64 + k] = f2b(v);
}

// ---------------- gather58 (fp8 src): xcat cols 64..127 ----------------
__global__ __launch_bounds__(256) void k_gather58(const int* __restrict__ rowptr,
                                                  const uint2* __restrict__ cedge,
                                                  const unsigned char* __restrict__ xf8,
                                                  unsigned short* __restrict__ xcat) {
    int t = blockIdx.x * 256 + threadIdx.x;
    int n = t >> 3, l = t & 7;
    if (n >= NN) return;
    int beg = rowptr[n], end = rowptr[n + 1];
    float acc[8] = {0, 0, 0, 0, 0, 0, 0, 0};
    for (int i = beg; i < end; i++) {
        uint2 e = cedge[i];
        float c = __uint_as_float(e.y);
        uint2 u = *(const uint2*)(xf8 + (size_t)e.x * 64 + l * 8);
        f32x2 p0 = __builtin_amdgcn_cvt_pk_f32_fp8(u.x, false);
        f32x2 p1 = __builtin_amdgcn_cvt_pk_f32_fp8(u.x, true);
        f32x2 p2 = __builtin_amdgcn_cvt_pk_f32_fp8(u.y, false);
        f32x2 p3 = __builtin_amdgcn_cvt_pk_f32_fp8(u.y, true);
        acc[0] += c * p0.x; acc[1] += c * p0.y;
        acc[2] += c * p1.x; acc[3] += c * p1.y;
        acc[4] += c * p2.x; acc[5] += c * p2.y;
        acc[6] += c * p3.x; acc[7] += c * p3.y;
    }
    bf16x8 o;
#pragma unroll
    for (int j = 0; j < 8; j++) o[j] = (short)f2b(acc[j]);
    *(bf16x8*)(xcat + (size_t)n * 128 + 64 + l * 8) = o;
}

// ---------------- MFMA GEMM 1: h = relu([x|tx1] @ Wt1^T + b1), bf16 out ------
__global__ __launch_bounds__(256) void k_mm1(const unsigned short* __restrict__ xcat,
                                             const unsigned short* __restrict__ Wt1,
                                             const float* __restrict__ b1,
                                             unsigned short* __restrict__ h) {
    int wave = threadIdx.x >> 6, lane = threadIdx.x & 63;
    int row0 = blockIdx.x * 64 + wave * 16;
    if (row0 >= NN) return;
    int ml = lane & 15, quad = lane >> 4;
    const bf16x8* Ap = (const bf16x8*)(xcat + (size_t)(row0 + ml) * 128 + quad * 8);
    bf16x8 a0 = Ap[0], a1 = Ap[4], a2 = Ap[8], a3 = Ap[12];
    for (int nt = 0; nt < 20; nt++) {
        const bf16x8* Bp = (const bf16x8*)(Wt1 + (size_t)(nt * 16 + ml) * 128 + quad * 8);
        f32x4 acc = {0.f, 0.f, 0.f, 0.f};
        acc = __builtin_amdgcn_mfma_f32_16x16x32_bf16(a0, Bp[0], acc, 0, 0, 0);
        acc = __builtin_amdgcn_mfma_f32_16x16x32_bf16(a1, Bp[4], acc, 0, 0, 0);
        acc = __builtin_amdgcn_mfma_f32_16x16x32_bf16(a2, Bp[8], acc, 0, 0, 0);
        acc = __builtin_amdgcn_mfma_f32_16x16x32_bf16(a3, Bp[12], acc, 0, 0, 0);
        int col = nt * 16 + ml;
        float bias = (col < 300) ? b1[col] : 0.0f;
#pragma unroll
        for (int r = 0; r < 4; r++) {
            int row = row0 + quad * 4 + r;
            float v = acc[r] + bias;
            v = v > 0.0f ? v : 0.0f;
            if (col >= 300) v = 0.0f;
            h[(size_t)row * 320 + col] = f2b(v);
        }
    }
}

// ---------------- MFMA GEMM 2: hp = h@W2_0 (fp32), hwf8 = h@W2_1 (fp8) -------
__global__ __launch_bounds__(256) void k_mm2(const unsigned short* __restrict__ h,
                                             const unsigned short* __restrict__ Wt2,
                                             float* __restrict__ hp,
                                             unsigned char* __restrict__ hwf8) {
    int wave = threadIdx.x >> 6, lane = threadIdx.x & 63;
    int row0 = blockIdx.x * 64 + wave * 16;
    if (row0 >= NN) return;
    int ml = lane & 15, quad = lane >> 4;
    const bf16x8* Ap = (const bf16x8*)(h + (size_t)(row0 + ml) * 320 + quad * 8);
    bf16x8 a[10];
#pragma unroll
    for (int s = 0; s < 10; s++) a[s] = Ap[s * 4];
    for (int nt = 0; nt < 13; nt++) {
        const bf16x8* Bp = (const bf16x8*)(Wt2 + (size_t)(nt * 16 + ml) * 320 + quad * 8);
        f32x4 acc = {0.f, 0.f, 0.f, 0.f};
#pragma unroll
        for (int s = 0; s < 10; s++)
            acc = __builtin_amdgcn_mfma_f32_16x16x32_bf16(a[s], Bp[s * 4], acc, 0, 0, 0);
        int j = nt * 16 + ml;
#pragma unroll
        for (int r = 0; r < 4; r++) {
            int row = row0 + quad * 4 + r;
            if (j < 104) hp[(size_t)row * 104 + j] = acc[r];
            else hwf8[(size_t)row * 128 + (j - 104)] = f2e4m3(acc[r]);
        }
    }
}

// ---------------- gather100 (fp8 src): tx2 fp32 ----------------
__global__ __launch_bounds__(256) void k_gather100(const int* __restrict__ rowptr,
                                                   const uint2* __restrict__ cedge,
                                                   const unsigned char* __restrict__ hwf8,
                                                   float* __restrict__ tx2) {
    int t = blockIdx.x * 256 + threadIdx.x;
    int n = t >> 4, l = t & 15;
    if (n >= NN || l >= 13) return;
    int beg = rowptr[n], end = rowptr[n + 1];
    float acc[8] = {0, 0, 0, 0, 0, 0, 0, 0};
    for (int i = beg; i < end; i++) {
        uint2 e = cedge[i];
        float c = __uint_as_float(e.y);
        uint2 u = *(const uint2*)(hwf8 + (size_t)e.x * 128 + l * 8);
        f32x2 p0 = __builtin_amdgcn_cvt_pk_f32_fp8(u.x, false);
        f32x2 p1 = __builtin_amdgcn_cvt_pk_f32_fp8(u.x, true);
        f32x2 p2 = __builtin_amdgcn_cvt_pk_f32_fp8(u.y, false);
        f32x2 p3 = __builtin_amdgcn_cvt_pk_f32_fp8(u.y, true);
        acc[0] += c * p0.x; acc[1] += c * p0.y;
        acc[2] += c * p1.x; acc[3] += c * p1.y;
        acc[4] += c * p2.x; acc[5] += c * p2.y;
        acc[6] += c * p3.x; acc[7] += c * p3.y;
    }
    f32x4 o0 = {acc[0], acc[1], acc[2], acc[3]};
    f32x4 o1 = {acc[4], acc[5], acc[6], acc[7]};
    *(f32x4*)(tx2 + (size_t)n * 104 + l * 8) = o0;
    *(f32x4*)(tx2 + (size_t)n * 104 + l * 8 + 4) = o1;
}

// ---------------- MFMA lin + fused x1 epilogue -> xm (fp32), zf8 (fp8) -------
__global__ __launch_bounds__(256) void k_mmlin(const unsigned short* __restrict__ xcat,
                                               const unsigned short* __restrict__ Wtl,
                                               const float* __restrict__ hp,
                                               const float* __restrict__ tx2,
                                               const float* __restrict__ b2,
                                               const float* __restrict__ l1b,
                                               const float* __restrict__ l2b,
                                               float* __restrict__ xm,
                                               unsigned char* __restrict__ zf8) {
    int wave = threadIdx.x >> 6, lane = threadIdx.x & 63;
    int row0 = blockIdx.x * 64 + wave * 16;
    if (row0 >= NN) return;
    int ml = lane & 15, quad = lane >> 4;
    const bf16x8* Ap = (const bf16x8*)(xcat + (size_t)(row0 + ml) * 128 + quad * 8);
    bf16x8 a0 = Ap[0], a1 = Ap[4];
    for (int nt = 0; nt < 13; nt++) {
        const bf16x8* Bp = (const bf16x8*)(Wtl + (size_t)(nt * 16 + ml) * 64 + quad * 8);
        f32x4 acc = {0.f, 0.f, 0.f, 0.f};
        acc = __builtin_amdgcn_mfma_f32_16x16x32_bf16(a0, Bp[0], acc, 0, 0, 0);
        acc = __builtin_amdgcn_mfma_f32_16x16x32_bf16(a1, Bp[4], acc, 0, 0, 0);
        int j = nt * 16 + ml;
        int jj = (j < 104) ? j : j - 104;
        float bb = 0.0f, lb = 0.0f;
        if (jj < 100) {
            bb = b2[jj];
            lb = (j < 104) ? l1b[jj] : l2b[jj];
        }
#pragma unroll
        for (int r = 0; r < 4; r++) {
            int row = row0 + quad * 4 + r;
            float x1v = hp[(size_t)row * 104 + jj] + tx2[(size_t)row * 104 + jj] + bb;
            x1v = x1v > 0.0f ? x1v : 0.0f;
            float lv = acc[r] + lb;
            lv = lv > 0.0f ? lv : 0.0f;
            float o = x1v + lv;
            if (j < 104) xm[(size_t)row * 104 + j] = o;
            else zf8[(size_t)row * 128 + (j - 104)] = f2e4m3(o);
        }
    }
}

// ---------------- edge scores + loss partials (fp8 z) ----------------
__global__ __launch_bounds__(256) void k_score(const unsigned char* __restrict__ zf8,
                                               const int* __restrict__ ei,
                                               const int* __restrict__ nei,
                                               double* __restrict__ red) {
    int tid = blockIdx.x * 256 + threadIdx.x;
    int sub = tid >> 4, l = tid & 15;
    int nsub = SB * 16;
    double acc = 0.0;
    for (int idx = sub; idx < 2 * NE; idx += nsub) {
        int a, b;
        if (idx < NE) {
            a = ei[idx];
            b = ei[NE + idx];
        } else {
            int e = idx - NE;
            a = nei[e];
            b = nei[NE + e];
        }
        float p = 0.0f;
        if (l < 13) {
            uint2 ua = *(const uint2*)(zf8 + (size_t)a * 128 + l * 8);
            uint2 ub = *(const uint2*)(zf8 + (size_t)b * 128 + l * 8);
            f32x2 a0 = __builtin_amdgcn_cvt_pk_f32_fp8(ua.x, false);
            f32x2 a1 = __builtin_amdgcn_cvt_pk_f32_fp8(ua.x, true);
            f32x2 a2 = __builtin_amdgcn_cvt_pk_f32_fp8(ua.y, false);
            f32x2 a3 = __builtin_amdgcn_cvt_pk_f32_fp8(ua.y, true);
            f32x2 b0 = __builtin_amdgcn_cvt_pk_f32_fp8(ub.x, false);
            f32x2 b1 = __builtin_amdgcn_cvt_pk_f32_fp8(ub.x, true);
            f32x2 b2 = __builtin_amdgcn_cvt_pk_f32_fp8(ub.y, false);
            f32x2 b3 = __builtin_amdgcn_cvt_pk_f32_fp8(ub.y, true);
            p = a0.x * b0.x + a0.y * b0.y + a1.x * b1.x + a1.y * b1.y +
                a2.x * b2.x + a2.y * b2.y + a3.x * b3.x + a3.y * b3.y;
        }
        for (int off = 8; off; off >>= 1) p += __shfl_xor(p, off, 16);
        if (l == 0) {
            float sg = 1.0f / (1.0f + expf(-p));
            float term = (idx < NE) ? logf(sg + 1e-15f) : logf(1.0f - sg + 1e-15f);
            acc += (double)term;
        }
    }
    __shared__ double sred[256];
    sred[threadIdx.x] = acc;
    __syncthreads();
    for (int s = 128; s; s >>= 1) {
        if (threadIdx.x < s) sred[threadIdx.x] += sred[threadIdx.x + s];
        __syncthreads();
    }
    if (threadIdx.x == 0) red[blockIdx.x] = sred[0];
}

__global__ void k_final(const double* __restrict__ red, const float* __restrict__ c1,
                        const float* __restrict__ c2, float* __restrict__ out) {
    double a = 0.0;
    for (int i = threadIdx.x; i < SB; i += 256) a += red[i];
    __shared__ double sred[256];
    sred[threadIdx.x] = a;
    __syncthreads();
    for (int s = 128; s; s >>= 1) {
        if (threadIdx.x < s) sred[threadIdx.x] += sred[threadIdx.x + s];
        __syncthreads();
    }
    if (threadIdx.x == 0) {
        out[NN] = (float)(-sred[0] / (double)NE);
        out[NN + 1] = c1[0];
        out[NN + 2] = c2[0];
    }
}

// ---------------- layer3: out[n]=xm@W3_0+b3, s[n]=xm@W3_1 ----------------
__global__ __launch_bounds__(256) void k_l3(const float* __restrict__ xm,
                                            const float* __restrict__ W30,
                                            const float* __restrict__ W31,
                                            const float* __restrict__ b3,
                                            float* __restrict__ out,
                                            float* __restrict__ s) {
    int lane = threadIdx.x & 31;
    int n = (blockIdx.x * 256 + threadIdx.x) >> 5;
    if (n >= NN) return;
    const float* row = xm + (size_t)n * 104;
    float d0 = 0.0f, d1 = 0.0f;
    for (int k = lane; k < 100; k += 32) {
        float v = row[k];
        d0 += v * W30[k];
        d1 += v * W31[k];
    }
    for (int off = 16; off; off >>= 1) {
        d0 += __shfl_down(d0, off, 32);
        d1 += __shfl_down(d1, off, 32);
    }
    if (lane == 0) {
        out[n] = d0 + b3[0];
        s[n] = d1;
    }
}

__global__ void k_gather1(const int* __restrict__ rowptr, const uint2* __restrict__ cedge,
                          const float* __restrict__ s, float* __restrict__ out) {
    int n = blockIdx.x * 256 + threadIdx.x;
    if (n >= NN) return;
    int beg = rowptr[n], end = rowptr[n + 1];
    float acc = 0.0f;
    for (int i = beg; i < end; i++) {
        uint2 e = cedge[i];
        acc += __uint_as_float(e.y) * s[e.x];
    }
    out[n] += acc;
}

extern "C" void kernel_launch(void* const* d_in, const int* in_sizes, int n_in,
                              void* d_out, int out_size, void* d_ws, size_t ws_size,
                              hipStream_t stream) {
    const float* x    = (const float*)d_in[0];
    const int*   ei   = (const int*)d_in[1];
    const int*   nei  = (const int*)d_in[2];
    const float* W1_0 = (const float*)d_in[3];
    const float* W1_1 = (const float*)d_in[4];
    const float* b1   = (const float*)d_in[5];
    const float* W2_0 = (const float*)d_in[6];
    const float* W2_1 = (const float*)d_in[7];
    const float* b2   = (const float*)d_in[8];
    const float* W3_0 = (const float*)d_in[9];
    const float* W3_1 = (const float*)d_in[10];
    const float* b3   = (const float*)d_in[11];
    const float* l1W  = (const float*)d_in[12];
    const float* l1b  = (const float*)d_in[13];
    const float* l2W  = (const float*)d_in[14];
    const float* l2b  = (const float*)d_in[15];
    const float* c1   = (const float*)d_in[16];
    const float* c2   = (const float*)d_in[17];
    float* out = (float*)d_out;
    float* w = (float*)d_ws;

    // workspace (float offsets)
    uint2*          cedge  = (uint2*)w;                           // 800000 int2
    int*            degs   = (int*)(w + 1600000);                 // 50000 [zeroed]
    int*            cnt    = (int*)(w + 1650000);                 // 50000 [zeroed]
    float*          dis    = w + 1700000;                         // 50000
    int*            rowptr = (int*)(w + 1750000);                 // 50001
    int*            cursor = (int*)(w + 1800008);                 // 50000
    float*          sbuf   = w + 1850008;                         // 50000
    int*            bsum   = (int*)(w + 1900008);                 // 256
    double*         red    = (double*)(w + 1900520);              // 2048 doubles
    unsigned short* xcat   = (unsigned short*)(w + 1908736);      // N*128 bf16
    unsigned short* Wt1    = (unsigned short*)(w + 5108736);      // 320*128 bf16
    unsigned short* Wt2    = (unsigned short*)(w + 5129216);      // 208*320 bf16
    unsigned short* Wtl    = (unsigned short*)(w + 5162496);      // 208*64 bf16
    float*          hp     = w + 5169152;                         // N*104 f
    unsigned char*  hwf8   = (unsigned char*)(w + 10369152);      // N*128 bytes
    float*          xm     = w + 11969152;                        // N*104 f
    unsigned char*  zf8    = (unsigned char*)(w + 17169152);      // N*128 bytes
    unsigned char*  xf8    = (unsigned char*)(w + 18769152);      // N*64 bytes
    unsigned short* h      = (unsigned short*)(w + 19569152);     // N*320 bf16
    float*          tx2    = w + 19569152;                        // N*104 f (overlays h)

    hipMemsetAsync(degs, 0, 100000 * sizeof(int), stream);  // degs + cnt contiguous

    // CSR build
    k_counts<<<(NE + 255) / 256, 256, 0, stream>>>(ei, degs, cnt);
    k_dis<<<(NN + 255) / 256, 256, 0, stream>>>(degs, dis);
    k_scan1<<<NB, 256, 0, stream>>>(cnt, rowptr, bsum);
    k_scan2<<<1, 256, 0, stream>>>(bsum, rowptr);
    k_scan3<<<NB, 256, 0, stream>>>(bsum, rowptr, cursor);
    k_fill<<<(NE + 255) / 256, 256, 0, stream>>>(ei, dis, cursor, cedge);

    // prep
    k_conv_x<<<NN * 64 / 256, 256, 0, stream>>>(x, xcat, xf8);
    k_prep_w1<<<160, 256, 0, stream>>>(W1_0, W1_1, Wt1);
    k_prep_w2<<<208, 320, 0, stream>>>(W2_0, W2_1, Wt2);
    k_prep_wl<<<208, 64, 0, stream>>>(l1W, l2W, Wtl);

    // layer 1
    k_gather58<<<(NN * 8 + 255) / 256, 256, 0, stream>>>(rowptr, cedge, xf8, xcat);
    k_mm1<<<(NN + 63) / 64, 256, 0, stream>>>(xcat, Wt1, b1, h);

    // layer 2
    k_mm2<<<(NN + 63) / 64, 256, 0, stream>>>(h, Wt2, hp, hwf8);
    k_gather100<<<NN * 16 / 256, 256, 0, stream>>>(rowptr, cedge, hwf8, tx2);

    // lin heads + x1 fusion
    k_mmlin<<<(NN + 63) / 64, 256, 0, stream>>>(xcat, Wtl, hp, tx2, b2, l1b, l2b, xm, zf8);

    // loss
    k_score<<<SB, 256, 0, stream>>>(zf8, ei, nei, red);
    k_final<<<1, 256, 0, stream>>>(red, c1, c2, out);

    // layer 3
    k_l3<<<NN * 32 / 256, 256, 0, stream>>>(xm, W3_0, W3_1, b3, out, sbuf);
    k_gather1<<<(NN + 255) / 256, 256, 0, stream>>>(rowptr, cedge, sbuf, out);
}

// Round 6
// 489.722 us; speedup vs baseline: 3.5025x; 1.0461x over previous
//
#include <hip/hip_runtime.h>
#include <math.h>

#define NN 50000
#define NE 800000
#define SB 1024   // score blocks
#define NB 196    // ceil(NN/256)

using bf16x8 = __attribute__((ext_vector_type(8))) short;
using f32x4  = __attribute__((ext_vector_type(4))) float;
using f32x2  = __attribute__((ext_vector_type(2))) float;
using i32x8  = __attribute__((ext_vector_type(8))) int;

__device__ __forceinline__ float b2f(short s) {
    union { unsigned u; float f; } v;
    v.u = ((unsigned)(unsigned short)s) << 16;
    return v.f;
}
__device__ __forceinline__ unsigned short f2b(float f) {
    union { float f; unsigned u; } v;
    v.f = f;
    unsigned r = v.u + 0x7fffu + ((v.u >> 16) & 1u);
    return (unsigned short)(r >> 16);
}
__device__ __forceinline__ unsigned char f2e4m3(float f) {
    return (unsigned char)(__builtin_amdgcn_cvt_pk_fp8_f32(f, f, 0, false) & 0xff);
}

// ---------------- fused degree counts ----------------
__global__ void k_counts(const int* __restrict__ ei, int* __restrict__ degs,
                         int* __restrict__ cnt) {
    int e = blockIdx.x * 256 + threadIdx.x;
    if (e < NE) {
        atomicAdd(&degs[ei[e]], 1);
        atomicAdd(&cnt[ei[NE + e]], 1);
    }
}

// ---------------- 3-phase scan (+ fused dis) ----------------
__global__ __launch_bounds__(256) void k_scan1(const int* __restrict__ cnt,
                                               const int* __restrict__ degs,
                                               float* __restrict__ dis,
                                               int* __restrict__ rowptr,
                                               int* __restrict__ bsum) {
    __shared__ int sdata[256];
    int i = blockIdx.x * 256 + threadIdx.x;
    int v = (i < NN) ? cnt[i] : 0;
    if (i < NN) {
        float d = (float)degs[i];
        dis[i] = d > 0.0f ? 1.0f / sqrtf(d) : 0.0f;
    }
    sdata[threadIdx.x] = v;
    __syncthreads();
    for (int s = 1; s < 256; s <<= 1) {
        int t = (threadIdx.x >= s) ? sdata[threadIdx.x - s] : 0;
        __syncthreads();
        sdata[threadIdx.x] += t;
        __syncthreads();
    }
    if (i < NN) rowptr[i] = sdata[threadIdx.x] - v;
    if (threadIdx.x == 255) bsum[blockIdx.x] = sdata[255];
}

__global__ __launch_bounds__(256) void k_scan2(int* __restrict__ bsum,
                                               int* __restrict__ rowptr) {
    __shared__ int sdata[256];
    int t = threadIdx.x;
    int v = (t < NB) ? bsum[t] : 0;
    sdata[t] = v;
    __syncthreads();
    for (int s = 1; s < 256; s <<= 1) {
        int x = (t >= s) ? sdata[t - s] : 0;
        __syncthreads();
        sdata[t] += x;
        __syncthreads();
    }
    if (t < NB) bsum[t] = sdata[t] - v;
    if (t == 255) rowptr[NN] = sdata[255];
}

__global__ __launch_bounds__(256) void k_scan3(const int* __restrict__ bsum,
                                               int* __restrict__ rowptr,
                                               int* __restrict__ cursor) {
    int i = blockIdx.x * 256 + threadIdx.x;
    if (i < NN) {
        int r = rowptr[i] + bsum[blockIdx.x];
        rowptr[i] = r;
        cursor[i] = r;
    }
}

// ---------------- CSR fill: packed {src, norm} ----------------
__global__ void k_fill(const int* __restrict__ ei, const float* __restrict__ dis,
                       int* __restrict__ cursor, uint2* __restrict__ cedge) {
    int e = blockIdx.x * 256 + threadIdx.x;
    if (e < NE) {
        int s = ei[e], d = ei[NE + e];
        int p = atomicAdd(&cursor[d], 1);
        uint2 v;
        v.x = (unsigned)s;
        v.y = __float_as_uint(-(dis[s] * dis[d]));
        cedge[p] = v;
    }
}

// ---------------- x -> bf16 (xcat cols 0..63) + fp8 copy (xf8) ----------------
__global__ void k_conv_x(const float* __restrict__ x, unsigned short* __restrict__ xcat,
                         unsigned char* __restrict__ xf8) {
    int t = blockIdx.x * 256 + threadIdx.x;
    int n = t >> 6, k = t & 63;
    float v = (k < 58) ? x[(size_t)n * 58 + k] : 0.0f;
    xcat[(size_t)n * 128 + k] = f2b(v);
    xf8[(size_t)n * 64 + k] = f2e4m3(v);
}

// ---------------- fused weight prep (bf16, transposed/padded) ----------------
__global__ void k_prep_w(const float* __restrict__ W1_0, const float* __restrict__ W1_1,
                         const float* __restrict__ W2_0, const float* __restrict__ W2_1,
                         const float* __restrict__ L1, const float* __restrict__ L2,
                         unsigned short* __restrict__ Wt1, unsigned short* __restrict__ Wt2,
                         unsigned short* __restrict__ Wtl) {
    int t = blockIdx.x * 256 + threadIdx.x;
    if (t < 40960) {  // Wt1: 320 x 128
        int c = t >> 7, k = t & 127;
        float v = 0.0f;
        if (c < 300) {
            if (k < 58) v = W1_0[k * 300 + c];
            else if (k >= 64 && k < 122) v = W1_1[(k - 64) * 300 + c];
        }
        Wt1[t] = f2b(v);
    } else if (t < 40960 + 66560) {  // Wt2: 208 x 320
        int u = t - 40960;
        int j = u / 320, k = u % 320;
        float v = 0.0f;
        if (k < 300) {
            if (j < 100) v = W2_0[k * 100 + j];
            else if (j >= 104 && j < 204) v = W2_1[k * 100 + (j - 104)];
        }
        Wt2[u] = f2b(v);
    } else if (t < 40960 + 66560 + 13312) {  // Wtl: 208 x 64
        int u = t - 40960 - 66560;
        int j = u >> 6, k = u & 63;
        float v = 0.0f;
        if (k < 58) {
            if (j < 100) v = L1[j * 58 + k];
            else if (j >= 104 && j < 204) v = L2[(j - 104) * 58 + k];
        }
        Wtl[u] = f2b(v);
    }
}

// ---------------- gather58 (fp8 src): xcat cols 64..127 ----------------
__global__ __launch_bounds__(256) void k_gather58(const int* __restrict__ rowptr,
                                                  const uint2* __restrict__ cedge,
                                                  const unsigned char* __restrict__ xf8,
                                                  unsigned short* __restrict__ xcat) {
    int t = blockIdx.x * 256 + threadIdx.x;
    int n = t >> 3, l = t & 7;
    if (n >= NN) return;
    int beg = rowptr[n], end = rowptr[n + 1];
    float acc[8] = {0, 0, 0, 0, 0, 0, 0, 0};
    for (int i = beg; i < end; i++) {
        uint2 e = cedge[i];
        float c = __uint_as_float(e.y);
        uint2 u = *(const uint2*)(xf8 + (size_t)e.x * 64 + l * 8);
        f32x2 p0 = __builtin_amdgcn_cvt_pk_f32_fp8(u.x, false);
        f32x2 p1 = __builtin_amdgcn_cvt_pk_f32_fp8(u.x, true);
        f32x2 p2 = __builtin_amdgcn_cvt_pk_f32_fp8(u.y, false);
        f32x2 p3 = __builtin_amdgcn_cvt_pk_f32_fp8(u.y, true);
        acc[0] += c * p0.x; acc[1] += c * p0.y;
        acc[2] += c * p1.x; acc[3] += c * p1.y;
        acc[4] += c * p2.x; acc[5] += c * p2.y;
        acc[6] += c * p3.x; acc[7] += c * p3.y;
    }
    bf16x8 o;
#pragma unroll
    for (int j = 0; j < 8; j++) o[j] = (short)f2b(acc[j]);
    *(bf16x8*)(xcat + (size_t)n * 128 + 64 + l * 8) = o;
}

// ---------------- MFMA GEMM 1: h = relu([x|tx1] @ Wt1^T + b1), bf16 out ------
__global__ __launch_bounds__(256) void k_mm1(const unsigned short* __restrict__ xcat,
                                             const unsigned short* __restrict__ Wt1,
                                             const float* __restrict__ b1,
                                             unsigned short* __restrict__ h) {
    int wave = threadIdx.x >> 6, lane = threadIdx.x & 63;
    int row0 = blockIdx.x * 64 + wave * 16;
    if (row0 >= NN) return;
    int ml = lane & 15, quad = lane >> 4;
    const bf16x8* Ap = (const bf16x8*)(xcat + (size_t)(row0 + ml) * 128 + quad * 8);
    bf16x8 a0 = Ap[0], a1 = Ap[4], a2 = Ap[8], a3 = Ap[12];
    for (int nt = 0; nt < 20; nt++) {
        const bf16x8* Bp = (const bf16x8*)(Wt1 + (size_t)(nt * 16 + ml) * 128 + quad * 8);
        f32x4 acc = {0.f, 0.f, 0.f, 0.f};
        acc = __builtin_amdgcn_mfma_f32_16x16x32_bf16(a0, Bp[0], acc, 0, 0, 0);
        acc = __builtin_amdgcn_mfma_f32_16x16x32_bf16(a1, Bp[4], acc, 0, 0, 0);
        acc = __builtin_amdgcn_mfma_f32_16x16x32_bf16(a2, Bp[8], acc, 0, 0, 0);
        acc = __builtin_amdgcn_mfma_f32_16x16x32_bf16(a3, Bp[12], acc, 0, 0, 0);
        int col = nt * 16 + ml;
        float bias = (col < 300) ? b1[col] : 0.0f;
#pragma unroll
        for (int r = 0; r < 4; r++) {
            int row = row0 + quad * 4 + r;
            float v = acc[r] + bias;
            v = v > 0.0f ? v : 0.0f;
            if (col >= 300) v = 0.0f;
            h[(size_t)row * 320 + col] = f2b(v);
        }
    }
}

// ---------------- MFMA GEMM 2: hp = h@W2_0 (fp32), hwf8 = h@W2_1 (fp8) -------
__global__ __launch_bounds__(256) void k_mm2(const unsigned short* __restrict__ h,
                                             const unsigned short* __restrict__ Wt2,
                                             float* __restrict__ hp,
                                             unsigned char* __restrict__ hwf8) {
    int wave = threadIdx.x >> 6, lane = threadIdx.x & 63;
    int row0 = blockIdx.x * 64 + wave * 16;
    if (row0 >= NN) return;
    int ml = lane & 15, quad = lane >> 4;
    const bf16x8* Ap = (const bf16x8*)(h + (size_t)(row0 + ml) * 320 + quad * 8);
    bf16x8 a[10];
#pragma unroll
    for (int s = 0; s < 10; s++) a[s] = Ap[s * 4];
    for (int nt = 0; nt < 13; nt++) {
        const bf16x8* Bp = (const bf16x8*)(Wt2 + (size_t)(nt * 16 + ml) * 320 + quad * 8);
        f32x4 acc = {0.f, 0.f, 0.f, 0.f};
#pragma unroll
        for (int s = 0; s < 10; s++)
            acc = __builtin_amdgcn_mfma_f32_16x16x32_bf16(a[s], Bp[s * 4], acc, 0, 0, 0);
        int j = nt * 16 + ml;
#pragma unroll
        for (int r = 0; r < 4; r++) {
            int row = row0 + quad * 4 + r;
            if (j < 104) hp[(size_t)row * 104 + j] = acc[r];
            else hwf8[(size_t)row * 128 + (j - 104)] = f2e4m3(acc[r]);
        }
    }
}

// ---------------- gather100 (fp8 src): tx2 fp32 ----------------
__global__ __launch_bounds__(256) void k_gather100(const int* __restrict__ rowptr,
                                                   const uint2* __restrict__ cedge,
                                                   const unsigned char* __restrict__ hwf8,
                                                   float* __restrict__ tx2) {
    int t = blockIdx.x * 256 + threadIdx.x;
    int n = t >> 4, l = t & 15;
    if (n >= NN || l >= 13) return;
    int beg = rowptr[n], end = rowptr[n + 1];
    float acc[8] = {0, 0, 0, 0, 0, 0, 0, 0};
    for (int i = beg; i < end; i++) {
        uint2 e = cedge[i];
        float c = __uint_as_float(e.y);
        uint2 u = *(const uint2*)(hwf8 + (size_t)e.x * 128 + l * 8);
        f32x2 p0 = __builtin_amdgcn_cvt_pk_f32_fp8(u.x, false);
        f32x2 p1 = __builtin_amdgcn_cvt_pk_f32_fp8(u.x, true);
        f32x2 p2 = __builtin_amdgcn_cvt_pk_f32_fp8(u.y, false);
        f32x2 p3 = __builtin_amdgcn_cvt_pk_f32_fp8(u.y, true);
        acc[0] += c * p0.x; acc[1] += c * p0.y;
        acc[2] += c * p1.x; acc[3] += c * p1.y;
        acc[4] += c * p2.x; acc[5] += c * p2.y;
        acc[6] += c * p3.x; acc[7] += c * p3.y;
    }
    f32x4 o0 = {acc[0], acc[1], acc[2], acc[3]};
    f32x4 o1 = {acc[4], acc[5], acc[6], acc[7]};
    *(f32x4*)(tx2 + (size_t)n * 104 + l * 8) = o0;
    *(f32x4*)(tx2 + (size_t)n * 104 + l * 8 + 4) = o1;
}

// ---------------- MFMA lin + fused x1 epilogue -> xm (fp32), zf8 (fp8) -------
__global__ __launch_bounds__(256) void k_mmlin(const unsigned short* __restrict__ xcat,
                                               const unsigned short* __restrict__ Wtl,
                                               const float* __restrict__ hp,
                                               const float* __restrict__ tx2,
                                               const float* __restrict__ b2,
                                               const float* __restrict__ l1b,
                                               const float* __restrict__ l2b,
                                               float* __restrict__ xm,
                                               unsigned char* __restrict__ zf8) {
    int wave = threadIdx.x >> 6, lane = threadIdx.x & 63;
    int row0 = blockIdx.x * 64 + wave * 16;
    if (row0 >= NN) return;
    int ml = lane & 15, quad = lane >> 4;
    const bf16x8* Ap = (const bf16x8*)(xcat + (size_t)(row0 + ml) * 128 + quad * 8);
    bf16x8 a0 = Ap[0], a1 = Ap[4];
    for (int nt = 0; nt < 13; nt++) {
        const bf16x8* Bp = (const bf16x8*)(Wtl + (size_t)(nt * 16 + ml) * 64 + quad * 8);
        f32x4 acc = {0.f, 0.f, 0.f, 0.f};
        acc = __builtin_amdgcn_mfma_f32_16x16x32_bf16(a0, Bp[0], acc, 0, 0, 0);
        acc = __builtin_amdgcn_mfma_f32_16x16x32_bf16(a1, Bp[4], acc, 0, 0, 0);
        int j = nt * 16 + ml;
        int jj = (j < 104) ? j : j - 104;
        float bb = 0.0f, lb = 0.0f;
        if (jj < 100) {
            bb = b2[jj];
            lb = (j < 104) ? l1b[jj] : l2b[jj];
        }
#pragma unroll
        for (int r = 0; r < 4; r++) {
            int row = row0 + quad * 4 + r;
            float x1v = hp[(size_t)row * 104 + jj] + tx2[(size_t)row * 104 + jj] + bb;
            x1v = x1v > 0.0f ? x1v : 0.0f;
            float lv = acc[r] + lb;
            lv = lv > 0.0f ? lv : 0.0f;
            float o = x1v + lv;
            if (j < 104) xm[(size_t)row * 104 + j] = o;
            else zf8[(size_t)row * 128 + (j - 104)] = f2e4m3(o);
        }
    }
}

// ---------------- edge scores via fp8 MFMA: 16 edges per wave-step -----------
__global__ __launch_bounds__(256) void k_score(const unsigned char* __restrict__ zf8,
                                               const int* __restrict__ ei,
                                               const int* __restrict__ nei,
                                               double* __restrict__ red) {
    int lane = threadIdx.x & 63;
    int wid = (blockIdx.x * 256 + threadIdx.x) >> 6;
    int nw = SB * 4;
    int ml = lane & 15, quad = lane >> 4;
    int dr = ml - quad * 4;  // diagonal reg if 0..3
    bool diag = (dr >= 0 && dr < 4);
    float facc = 0.0f;
    const int G = (2 * NE) / 16;  // 100000 groups of 16 edges
    for (int g = wid; g < G; g += nw) {
        int base = g * 16;
        int a, b;
        if (base < NE) {
            a = ei[base + ml];
            b = ei[NE + base + ml];
        } else {
            a = nei[base - NE + ml];
            b = nei[base + ml];
        }
        i32x8 av = *(const i32x8*)(zf8 + (size_t)a * 128 + quad * 32);
        i32x8 bv = *(const i32x8*)(zf8 + (size_t)b * 128 + quad * 32);
        f32x4 d = {0.f, 0.f, 0.f, 0.f};
        d = __builtin_amdgcn_mfma_scale_f32_16x16x128_f8f6f4(
                av, bv, d, 0, 0, 0, 0x7f7f7f7f, 0, 0x7f7f7f7f);
        if (diag) {
            float p = d[dr];
            float sg = 1.0f / (1.0f + expf(-p));
            float term = (base < NE) ? logf(sg + 1e-15f) : logf(1.0f - sg + 1e-15f);
            facc += term;
        }
    }
    __shared__ double sred[256];
    sred[threadIdx.x] = (double)facc;
    __syncthreads();
    for (int s = 128; s; s >>= 1) {
        if (threadIdx.x < s) sred[threadIdx.x] += sred[threadIdx.x + s];
        __syncthreads();
    }
    if (threadIdx.x == 0) red[blockIdx.x] = sred[0];
}

__global__ void k_final(const double* __restrict__ red, const float* __restrict__ c1,
                        const float* __restrict__ c2, float* __restrict__ out) {
    double a = 0.0;
    for (int i = threadIdx.x; i < SB; i += 256) a += red[i];
    __shared__ double sred[256];
    sred[threadIdx.x] = a;
    __syncthreads();
    for (int s = 128; s; s >>= 1) {
        if (threadIdx.x < s) sred[threadIdx.x] += sred[threadIdx.x + s];
        __syncthreads();
    }
    if (threadIdx.x == 0) {
        out[NN] = (float)(-sred[0] / (double)NE);
        out[NN + 1] = c1[0];
        out[NN + 2] = c2[0];
    }
}

// ---------------- layer3: out[n]=xm@W3_0+b3, s[n]=xm@W3_1 ----------------
__global__ __launch_bounds__(256) void k_l3(const float* __restrict__ xm,
                                            const float* __restrict__ W30,
                                            const float* __restrict__ W31,
                                            const float* __restrict__ b3,
                                            float* __restrict__ out,
                                            float* __restrict__ s) {
    int lane = threadIdx.x & 31;
    int n = (blockIdx.x * 256 + threadIdx.x) >> 5;
    if (n >= NN) return;
    const float* row = xm + (size_t)n * 104;
    float d0 = 0.0f, d1 = 0.0f;
    for (int k = lane; k < 100; k += 32) {
        float v = row[k];
        d0 += v * W30[k];
        d1 += v * W31[k];
    }
    for (int off = 16; off; off >>= 1) {
        d0 += __shfl_down(d0, off, 32);
        d1 += __shfl_down(d1, off, 32);
    }
    if (lane == 0) {
        out[n] = d0 + b3[0];
        s[n] = d1;
    }
}

__global__ void k_gather1(const int* __restrict__ rowptr, const uint2* __restrict__ cedge,
                          const float* __restrict__ s, float* __restrict__ out) {
    int n = blockIdx.x * 256 + threadIdx.x;
    if (n >= NN) return;
    int beg = rowptr[n], end = rowptr[n + 1];
    float acc = 0.0f;
    for (int i = beg; i < end; i++) {
        uint2 e = cedge[i];
        acc += __uint_as_float(e.y) * s[e.x];
    }
    out[n] += acc;
}

extern "C" void kernel_launch(void* const* d_in, const int* in_sizes, int n_in,
                              void* d_out, int out_size, void* d_ws, size_t ws_size,
                              hipStream_t stream) {
    const float* x    = (const float*)d_in[0];
    const int*   ei   = (const int*)d_in[1];
    const int*   nei  = (const int*)d_in[2];
    const float* W1_0 = (const float*)d_in[3];
    const float* W1_1 = (const float*)d_in[4];
    const float* b1   = (const float*)d_in[5];
    const float* W2_0 = (const float*)d_in[6];
    const float* W2_1 = (const float*)d_in[7];
    const float* b2   = (const float*)d_in[8];
    const float* W3_0 = (const float*)d_in[9];
    const float* W3_1 = (const float*)d_in[10];
    const float* b3   = (const float*)d_in[11];
    const float* l1W  = (const float*)d_in[12];
    const float* l1b  = (const float*)d_in[13];
    const float* l2W  = (const float*)d_in[14];
    const float* l2b  = (const float*)d_in[15];
    const float* c1   = (const float*)d_in[16];
    const float* c2   = (const float*)d_in[17];
    float* out = (float*)d_out;
    float* w = (float*)d_ws;

    // workspace (float offsets)
    uint2*          cedge  = (uint2*)w;                           // 800000 int2
    int*            degs   = (int*)(w + 1600000);                 // 50000 [zeroed]
    int*            cnt    = (int*)(w + 1650000);                 // 50000 [zeroed]
    float*          dis    = w + 1700000;                         // 50000
    int*            rowptr = (int*)(w + 1750000);                 // 50001
    int*            cursor = (int*)(w + 1800008);                 // 50000
    float*          sbuf   = w + 1850008;                         // 50000
    int*            bsum   = (int*)(w + 1900008);                 // 256
    double*         red    = (double*)(w + 1900520);              // 1024 doubles
    unsigned short* xcat   = (unsigned short*)(w + 1908736);      // N*128 bf16
    unsigned short* Wt1    = (unsigned short*)(w + 5108736);      // 320*128 bf16
    unsigned short* Wt2    = (unsigned short*)(w + 5129216);      // 208*320 bf16
    unsigned short* Wtl    = (unsigned short*)(w + 5162496);      // 208*64 bf16
    float*          hp     = w + 5169152;                         // N*104 f
    unsigned char*  hwf8   = (unsigned char*)(w + 10369152);      // N*128 bytes
    float*          xm     = w + 11969152;                        // N*104 f
    unsigned char*  zf8    = (unsigned char*)(w + 17169152);      // N*128 bytes
    unsigned char*  xf8    = (unsigned char*)(w + 18769152);      // N*64 bytes
    unsigned short* h      = (unsigned short*)(w + 19569152);     // N*320 bf16
    float*          tx2    = w + 19569152;                        // N*104 f (overlays h)

    hipMemsetAsync(degs, 0, 100000 * sizeof(int), stream);  // degs + cnt contiguous

    // CSR build
    k_counts<<<(NE + 255) / 256, 256, 0, stream>>>(ei, degs, cnt);
    k_scan1<<<NB, 256, 0, stream>>>(cnt, degs, dis, rowptr, bsum);
    k_scan2<<<1, 256, 0, stream>>>(bsum, rowptr);
    k_scan3<<<NB, 256, 0, stream>>>(bsum, rowptr, cursor);
    k_fill<<<(NE + 255) / 256, 256, 0, stream>>>(ei, dis, cursor, cedge);

    // prep
    k_conv_x<<<NN * 64 / 256, 256, 0, stream>>>(x, xcat, xf8);
    k_prep_w<<<473, 256, 0, stream>>>(W1_0, W1_1, W2_0, W2_1, l1W, l2W, Wt1, Wt2, Wtl);

    // layer 1
    k_gather58<<<(NN * 8 + 255) / 256, 256, 0, stream>>>(rowptr, cedge, xf8, xcat);
    k_mm1<<<(NN + 63) / 64, 256, 0, stream>>>(xcat, Wt1, b1, h);

    // layer 2
    k_mm2<<<(NN + 63) / 64, 256, 0, stream>>>(h, Wt2, hp, hwf8);
    k_gather100<<<NN * 16 / 256, 256, 0, stream>>>(rowptr, cedge, hwf8, tx2);

    // lin heads + x1 fusion
    k_mmlin<<<(NN + 63) / 64, 256, 0, stream>>>(xcat, Wtl, hp, tx2, b2, l1b, l2b, xm, zf8);

    // loss
    k_score<<<SB, 256, 0, stream>>>(zf8, ei, nei, red);
    k_final<<<1, 256, 0, stream>>>(red, c1, c2, out);

    // layer 3
    k_l3<<<NN * 32 / 256, 256, 0, stream>>>(xm, W3_0, W3_1, b3, out, sbuf);
    k_gather1<<<(NN + 255) / 256, 256, 0, stream>>>(rowptr, cedge, sbuf, out);
}

// Round 7
// 418.214 us; speedup vs baseline: 4.1013x; 1.1710x over previous
//
#include <hip/hip_runtime.h>
#include <math.h>

#define NN 50000
#define NE 800000
#define SB 1024   // score blocks
#define NB 196    // ceil(NN/256)

using bf16x8 = __attribute__((ext_vector_type(8))) short;
using f32x4  = __attribute__((ext_vector_type(4))) float;
using f32x2  = __attribute__((ext_vector_type(2))) float;
using i32x8  = __attribute__((ext_vector_type(8))) int;

__device__ __forceinline__ float b2f(short s) {
    union { unsigned u; float f; } v;
    v.u = ((unsigned)(unsigned short)s) << 16;
    return v.f;
}
__device__ __forceinline__ unsigned short f2b(float f) {
    union { float f; unsigned u; } v;
    v.f = f;
    unsigned r = v.u + 0x7fffu + ((v.u >> 16) & 1u);
    return (unsigned short)(r >> 16);
}
__device__ __forceinline__ unsigned char f2e4m3(float f) {
    return (unsigned char)(__builtin_amdgcn_cvt_pk_fp8_f32(f, f, 0, false) & 0xff);
}

// ---------------- fused degree counts ----------------
__global__ void k_counts(const int* __restrict__ ei, int* __restrict__ degs,
                         int* __restrict__ cnt) {
    int e = blockIdx.x * 256 + threadIdx.x;
    if (e < NE) {
        atomicAdd(&degs[ei[e]], 1);
        atomicAdd(&cnt[ei[NE + e]], 1);
    }
}

// ---------------- 3-phase scan (+ fused dis) ----------------
__global__ __launch_bounds__(256) void k_scan1(const int* __restrict__ cnt,
                                               const int* __restrict__ degs,
                                               float* __restrict__ dis,
                                               int* __restrict__ rowptr,
                                               int* __restrict__ bsum) {
    __shared__ int sdata[256];
    int i = blockIdx.x * 256 + threadIdx.x;
    int v = (i < NN) ? cnt[i] : 0;
    if (i < NN) {
        float d = (float)degs[i];
        dis[i] = d > 0.0f ? 1.0f / sqrtf(d) : 0.0f;
    }
    sdata[threadIdx.x] = v;
    __syncthreads();
    for (int s = 1; s < 256; s <<= 1) {
        int t = (threadIdx.x >= s) ? sdata[threadIdx.x - s] : 0;
        __syncthreads();
        sdata[threadIdx.x] += t;
        __syncthreads();
    }
    if (i < NN) rowptr[i] = sdata[threadIdx.x] - v;
    if (threadIdx.x == 255) bsum[blockIdx.x] = sdata[255];
}

__global__ __launch_bounds__(256) void k_scan2(int* __restrict__ bsum,
                                               int* __restrict__ rowptr) {
    __shared__ int sdata[256];
    int t = threadIdx.x;
    int v = (t < NB) ? bsum[t] : 0;
    sdata[t] = v;
    __syncthreads();
    for (int s = 1; s < 256; s <<= 1) {
        int x = (t >= s) ? sdata[t - s] : 0;
        __syncthreads();
        sdata[t] += x;
        __syncthreads();
    }
    if (t < NB) bsum[t] = sdata[t] - v;
    if (t == 255) rowptr[NN] = sdata[255];
}

__global__ __launch_bounds__(256) void k_scan3(const int* __restrict__ bsum,
                                               int* __restrict__ rowptr,
                                               int* __restrict__ cursor) {
    int i = blockIdx.x * 256 + threadIdx.x;
    if (i < NN) {
        int r = rowptr[i] + bsum[blockIdx.x];
        rowptr[i] = r;
        cursor[i] = r;
    }
}

// ---------------- CSR fill: packed {src, norm} ----------------
__global__ void k_fill(const int* __restrict__ ei, const float* __restrict__ dis,
                       int* __restrict__ cursor, uint2* __restrict__ cedge) {
    int e = blockIdx.x * 256 + threadIdx.x;
    if (e < NE) {
        int s = ei[e], d = ei[NE + e];
        int p = atomicAdd(&cursor[d], 1);
        uint2 v;
        v.x = (unsigned)s;
        v.y = __float_as_uint(-(dis[s] * dis[d]));
        cedge[p] = v;
    }
}

// ---------------- x -> bf16 (xcat cols 0..63) + fp8 copy (xf8) ----------------
__global__ void k_conv_x(const float* __restrict__ x, unsigned short* __restrict__ xcat,
                         unsigned char* __restrict__ xf8) {
    int t = blockIdx.x * 256 + threadIdx.x;
    int n = t >> 6, k = t & 63;
    float v = (k < 58) ? x[(size_t)n * 58 + k] : 0.0f;
    xcat[(size_t)n * 128 + k] = f2b(v);
    xf8[(size_t)n * 64 + k] = f2e4m3(v);
}

// ------- weight prep: FRAGMENT-ORDER layout ((nt*S+s)*64+lane)*8 -------------
__global__ void k_prep_w(const float* __restrict__ W1_0, const float* __restrict__ W1_1,
                         const float* __restrict__ W2_0, const float* __restrict__ W2_1,
                         const float* __restrict__ L1, const float* __restrict__ L2,
                         unsigned short* __restrict__ Wt1f, unsigned short* __restrict__ Wt2f,
                         unsigned short* __restrict__ Wtlf) {
    int t = blockIdx.x * 256 + threadIdx.x;
    if (t < 40960) {  // Wt1f: 20 nt x 4 frags x 512
        int f = t >> 9, lane = (t >> 3) & 63, j = t & 7;
        int nt = f >> 2, s = f & 3;
        int ml = lane & 15, quad = lane >> 4;
        int k = s * 32 + quad * 8 + j;
        int col = nt * 16 + ml;
        float v = 0.0f;
        if (col < 300) {
            if (k < 58) v = W1_0[k * 300 + col];
            else if (k >= 64 && k < 122) v = W1_1[(k - 64) * 300 + col];
        }
        Wt1f[t] = f2b(v);
    } else if (t < 107520) {  // Wt2f: 13 nt x 10 frags x 512
        int u = t - 40960;
        int f = u >> 9, lane = (u >> 3) & 63, j = u & 7;
        int nt = f / 10, s = f - nt * 10;
        int ml = lane & 15, quad = lane >> 4;
        int k = s * 32 + quad * 8 + j;
        int col = nt * 16 + ml;
        float v = 0.0f;
        if (k < 300) {
            if (col < 100) v = W2_0[k * 100 + col];
            else if (col >= 104 && col < 204) v = W2_1[k * 100 + (col - 104)];
        }
        Wt2f[u] = f2b(v);
    } else if (t < 120832) {  // Wtlf: 13 nt x 2 frags x 512
        int u = t - 107520;
        int f = u >> 9, lane = (u >> 3) & 63, j = u & 7;
        int nt = f >> 1, s = f & 1;
        int ml = lane & 15, quad = lane >> 4;
        int k = s * 32 + quad * 8 + j;
        int col = nt * 16 + ml;
        float v = 0.0f;
        if (k < 58) {
            if (col < 100) v = L1[col * 58 + k];
            else if (col >= 104 && col < 204) v = L2[(col - 104) * 58 + k];
        }
        Wtlf[u] = f2b(v);
    }
}

// ---------------- gather58 (fp8 src): xcat cols 64..127 ----------------
__global__ __launch_bounds__(256) void k_gather58(const int* __restrict__ rowptr,
                                                  const uint2* __restrict__ cedge,
                                                  const unsigned char* __restrict__ xf8,
                                                  unsigned short* __restrict__ xcat) {
    int t = blockIdx.x * 256 + threadIdx.x;
    int n = t >> 3, l = t & 7;
    if (n >= NN) return;
    int beg = rowptr[n], end = rowptr[n + 1];
    float acc[8] = {0, 0, 0, 0, 0, 0, 0, 0};
    for (int i = beg; i < end; i++) {
        uint2 e = cedge[i];
        float c = __uint_as_float(e.y);
        uint2 u = *(const uint2*)(xf8 + (size_t)e.x * 64 + l * 8);
        f32x2 p0 = __builtin_amdgcn_cvt_pk_f32_fp8(u.x, false);
        f32x2 p1 = __builtin_amdgcn_cvt_pk_f32_fp8(u.x, true);
        f32x2 p2 = __builtin_amdgcn_cvt_pk_f32_fp8(u.y, false);
        f32x2 p3 = __builtin_amdgcn_cvt_pk_f32_fp8(u.y, true);
        acc[0] += c * p0.x; acc[1] += c * p0.y;
        acc[2] += c * p1.x; acc[3] += c * p1.y;
        acc[4] += c * p2.x; acc[5] += c * p2.y;
        acc[6] += c * p3.x; acc[7] += c * p3.y;
    }
    bf16x8 o;
#pragma unroll
    for (int j = 0; j < 8; j++) o[j] = (short)f2b(acc[j]);
    *(bf16x8*)(xcat + (size_t)n * 128 + 64 + l * 8) = o;
}

// ------- fused MFMA GEMM: h = relu([x|tx1]@W1^T+b1) in LDS, then
//         hp = h@W2_0 (fp32) & hwf8 = h@W2_1 (fp8). B staged via LDS dbuf. ----
__global__ __launch_bounds__(256) void k_mm12(const unsigned short* __restrict__ xcat,
                                              const unsigned short* __restrict__ Wt1f,
                                              const float* __restrict__ b1,
                                              const unsigned short* __restrict__ Wt2f,
                                              float* __restrict__ hp,
                                              unsigned char* __restrict__ hwf8) {
    __shared__ __attribute__((aligned(16))) unsigned short hs[64 * 328];  // 41 KB, stride 328 breaks conflicts
    __shared__ __attribute__((aligned(16))) unsigned short bst[2][5120];  // 2 x 10 KB
    int tid = threadIdx.x;
    int wave = tid >> 6, lane = tid & 63, ml = lane & 15, quad = lane >> 4;
    int row0 = blockIdx.x * 64;
    int rw = row0 + wave * 16;

    // phase-1 A fragments (clamped rows for tail block)
    int ar = rw + ml; if (ar >= NN) ar = NN - 1;
    const bf16x8* Ap = (const bf16x8*)(xcat + (size_t)ar * 128 + quad * 8);
    bf16x8 a0 = Ap[0], a1 = Ap[4], a2 = Ap[8], a3 = Ap[12];

    // stage Wt1 nt=0 (2048 elems = 256 threads x bf16x8)
    ((bf16x8*)bst[0])[tid] = ((const bf16x8*)Wt1f)[tid];
    __syncthreads();

    for (int nt = 0; nt < 20; nt++) {
        if (nt + 1 < 20)
            ((bf16x8*)bst[(nt + 1) & 1])[tid] =
                ((const bf16x8*)(Wt1f + (size_t)(nt + 1) * 2048))[tid];
        const bf16x8* Bp = (const bf16x8*)bst[nt & 1];
        f32x4 acc = {0.f, 0.f, 0.f, 0.f};
        acc = __builtin_amdgcn_mfma_f32_16x16x32_bf16(a0, Bp[0 * 64 + lane], acc, 0, 0, 0);
        acc = __builtin_amdgcn_mfma_f32_16x16x32_bf16(a1, Bp[1 * 64 + lane], acc, 0, 0, 0);
        acc = __builtin_amdgcn_mfma_f32_16x16x32_bf16(a2, Bp[2 * 64 + lane], acc, 0, 0, 0);
        acc = __builtin_amdgcn_mfma_f32_16x16x32_bf16(a3, Bp[3 * 64 + lane], acc, 0, 0, 0);
        int col = nt * 16 + ml;
        float bias = (col < 300) ? b1[col] : 0.0f;
#pragma unroll
        for (int r = 0; r < 4; r++) {
            float v = acc[r] + bias;
            v = v > 0.0f ? v : 0.0f;
            if (col >= 300) v = 0.0f;
            hs[(wave * 16 + quad * 4 + r) * 328 + col] = f2b(v);
        }
        __syncthreads();
    }

    // stage Wt2 nt=0 (640 bf16x8)
    for (int i = tid; i < 640; i += 256)
        ((bf16x8*)bst[0])[i] = ((const bf16x8*)Wt2f)[i];
    // phase-2 A fragments from LDS h
    bf16x8 A2[10];
#pragma unroll
    for (int s = 0; s < 10; s++)
        A2[s] = *(const bf16x8*)(hs + (wave * 16 + ml) * 328 + s * 32 + quad * 8);
    __syncthreads();

    for (int nt = 0; nt < 13; nt++) {
        if (nt + 1 < 13)
            for (int i = tid; i < 640; i += 256)
                ((bf16x8*)bst[(nt + 1) & 1])[i] =
                    ((const bf16x8*)(Wt2f + (size_t)(nt + 1) * 5120))[i];
        const bf16x8* Bp = (const bf16x8*)bst[nt & 1];
        f32x4 acc = {0.f, 0.f, 0.f, 0.f};
#pragma unroll
        for (int s = 0; s < 10; s++)
            acc = __builtin_amdgcn_mfma_f32_16x16x32_bf16(A2[s], Bp[s * 64 + lane], acc, 0, 0, 0);
        int j = nt * 16 + ml;
#pragma unroll
        for (int r = 0; r < 4; r++) {
            int row = rw + quad * 4 + r;
            if (row < NN) {
                if (j < 104) hp[(size_t)row * 104 + j] = acc[r];
                else hwf8[(size_t)row * 128 + (j - 104)] = f2e4m3(acc[r]);
            }
        }
        __syncthreads();
    }
}

// ---------------- gather100 (fp8 src): tx2 fp32 ----------------
__global__ __launch_bounds__(256) void k_gather100(const int* __restrict__ rowptr,
                                                   const uint2* __restrict__ cedge,
                                                   const unsigned char* __restrict__ hwf8,
                                                   float* __restrict__ tx2) {
    int t = blockIdx.x * 256 + threadIdx.x;
    int n = t >> 4, l = t & 15;
    if (n >= NN || l >= 13) return;
    int beg = rowptr[n], end = rowptr[n + 1];
    float acc[8] = {0, 0, 0, 0, 0, 0, 0, 0};
    for (int i = beg; i < end; i++) {
        uint2 e = cedge[i];
        float c = __uint_as_float(e.y);
        uint2 u = *(const uint2*)(hwf8 + (size_t)e.x * 128 + l * 8);
        f32x2 p0 = __builtin_amdgcn_cvt_pk_f32_fp8(u.x, false);
        f32x2 p1 = __builtin_amdgcn_cvt_pk_f32_fp8(u.x, true);
        f32x2 p2 = __builtin_amdgcn_cvt_pk_f32_fp8(u.y, false);
        f32x2 p3 = __builtin_amdgcn_cvt_pk_f32_fp8(u.y, true);
        acc[0] += c * p0.x; acc[1] += c * p0.y;
        acc[2] += c * p1.x; acc[3] += c * p1.y;
        acc[4] += c * p2.x; acc[5] += c * p2.y;
        acc[6] += c * p3.x; acc[7] += c * p3.y;
    }
    f32x4 o0 = {acc[0], acc[1], acc[2], acc[3]};
    f32x4 o1 = {acc[4], acc[5], acc[6], acc[7]};
    *(f32x4*)(tx2 + (size_t)n * 104 + l * 8) = o0;
    *(f32x4*)(tx2 + (size_t)n * 104 + l * 8 + 4) = o1;
}

// ---------------- MFMA lin + fused x1 epilogue -> xm (fp32), zf8 (fp8) -------
__global__ __launch_bounds__(256) void k_mmlin(const unsigned short* __restrict__ xcat,
                                               const unsigned short* __restrict__ Wtlf,
                                               const float* __restrict__ hp,
                                               const float* __restrict__ tx2,
                                               const float* __restrict__ b2,
                                               const float* __restrict__ l1b,
                                               const float* __restrict__ l2b,
                                               float* __restrict__ xm,
                                               unsigned char* __restrict__ zf8) {
    int wave = threadIdx.x >> 6, lane = threadIdx.x & 63;
    int row0 = blockIdx.x * 64 + wave * 16;
    if (row0 >= NN) return;
    int ml = lane & 15, quad = lane >> 4;
    const bf16x8* Ap = (const bf16x8*)(xcat + (size_t)(row0 + ml) * 128 + quad * 8);
    bf16x8 a0 = Ap[0], a1 = Ap[4];
    for (int nt = 0; nt < 13; nt++) {
        bf16x8 b0 = *(const bf16x8*)(Wtlf + (size_t)((nt * 2 + 0) * 64 + lane) * 8);
        bf16x8 b1f = *(const bf16x8*)(Wtlf + (size_t)((nt * 2 + 1) * 64 + lane) * 8);
        f32x4 acc = {0.f, 0.f, 0.f, 0.f};
        acc = __builtin_amdgcn_mfma_f32_16x16x32_bf16(a0, b0, acc, 0, 0, 0);
        acc = __builtin_amdgcn_mfma_f32_16x16x32_bf16(a1, b1f, acc, 0, 0, 0);
        int j = nt * 16 + ml;
        int jj = (j < 104) ? j : j - 104;
        float bb = 0.0f, lb = 0.0f;
        if (jj < 100) {
            bb = b2[jj];
            lb = (j < 104) ? l1b[jj] : l2b[jj];
        }
#pragma unroll
        for (int r = 0; r < 4; r++) {
            int row = row0 + quad * 4 + r;
            float x1v = hp[(size_t)row * 104 + jj] + tx2[(size_t)row * 104 + jj] + bb;
            x1v = x1v > 0.0f ? x1v : 0.0f;
            float lv = acc[r] + lb;
            lv = lv > 0.0f ? lv : 0.0f;
            float o = x1v + lv;
            if (j < 104) xm[(size_t)row * 104 + j] = o;
            else zf8[(size_t)row * 128 + (j - 104)] = f2e4m3(o);
        }
    }
}

// ---------------- edge scores via fp8 MFMA: 16 edges per wave-step -----------
__global__ __launch_bounds__(256) void k_score(const unsigned char* __restrict__ zf8,
                                               const int* __restrict__ ei,
                                               const int* __restrict__ nei,
                                               double* __restrict__ red) {
    int lane = threadIdx.x & 63;
    int wid = (blockIdx.x * 256 + threadIdx.x) >> 6;
    int nw = SB * 4;
    int ml = lane & 15, quad = lane >> 4;
    int dr = ml - quad * 4;  // diagonal reg if 0..3
    bool diag = (dr >= 0 && dr < 4);
    float facc = 0.0f;
    const int G = (2 * NE) / 16;
    for (int g = wid; g < G; g += nw) {
        int base = g * 16;
        int a, b;
        if (base < NE) {
            a = ei[base + ml];
            b = ei[NE + base + ml];
        } else {
            a = nei[base - NE + ml];
            b = nei[base + ml];
        }
        i32x8 av = *(const i32x8*)(zf8 + (size_t)a * 128 + quad * 32);
        i32x8 bv = *(const i32x8*)(zf8 + (size_t)b * 128 + quad * 32);
        f32x4 d = {0.f, 0.f, 0.f, 0.f};
        d = __builtin_amdgcn_mfma_scale_f32_16x16x128_f8f6f4(
                av, bv, d, 0, 0, 0, 0x7f7f7f7f, 0, 0x7f7f7f7f);
        if (diag) {
            float p = d[dr];
            float sg = 1.0f / (1.0f + expf(-p));
            float term = (base < NE) ? logf(sg + 1e-15f) : logf(1.0f - sg + 1e-15f);
            facc += term;
        }
    }
    __shared__ double sred[256];
    sred[threadIdx.x] = (double)facc;
    __syncthreads();
    for (int s = 128; s; s >>= 1) {
        if (threadIdx.x < s) sred[threadIdx.x] += sred[threadIdx.x + s];
        __syncthreads();
    }
    if (threadIdx.x == 0) red[blockIdx.x] = sred[0];
}

__global__ void k_final(const double* __restrict__ red, const float* __restrict__ c1,
                        const float* __restrict__ c2, float* __restrict__ out) {
    double a = 0.0;
    for (int i = threadIdx.x; i < SB; i += 256) a += red[i];
    __shared__ double sred[256];
    sred[threadIdx.x] = a;
    __syncthreads();
    for (int s = 128; s; s >>= 1) {
        if (threadIdx.x < s) sred[threadIdx.x] += sred[threadIdx.x + s];
        __syncthreads();
    }
    if (threadIdx.x == 0) {
        out[NN] = (float)(-sred[0] / (double)NE);
        out[NN + 1] = c1[0];
        out[NN + 2] = c2[0];
    }
}

// ---------------- layer3: out[n]=xm@W3_0+b3, s[n]=xm@W3_1 ----------------
__global__ __launch_bounds__(256) void k_l3(const float* __restrict__ xm,
                                            const float* __restrict__ W30,
                                            const float* __restrict__ W31,
                                            const float* __restrict__ b3,
                                            float* __restrict__ out,
                                            float* __restrict__ s) {
    int lane = threadIdx.x & 31;
    int n = (blockIdx.x * 256 + threadIdx.x) >> 5;
    if (n >= NN) return;
    const float* row = xm + (size_t)n * 104;
    float d0 = 0.0f, d1 = 0.0f;
    for (int k = lane; k < 100; k += 32) {
        float v = row[k];
        d0 += v * W30[k];
        d1 += v * W31[k];
    }
    for (int off = 16; off; off >>= 1) {
        d0 += __shfl_down(d0, off, 32);
        d1 += __shfl_down(d1, off, 32);
    }
    if (lane == 0) {
        out[n] = d0 + b3[0];
        s[n] = d1;
    }
}

__global__ void k_gather1(const int* __restrict__ rowptr, const uint2* __restrict__ cedge,
                          const float* __restrict__ s, float* __restrict__ out) {
    int n = blockIdx.x * 256 + threadIdx.x;
    if (n >= NN) return;
    int beg = rowptr[n], end = rowptr[n + 1];
    float acc = 0.0f;
    for (int i = beg; i < end; i++) {
        uint2 e = cedge[i];
        acc += __uint_as_float(e.y) * s[e.x];
    }
    out[n] += acc;
}

extern "C" void kernel_launch(void* const* d_in, const int* in_sizes, int n_in,
                              void* d_out, int out_size, void* d_ws, size_t ws_size,
                              hipStream_t stream) {
    const float* x    = (const float*)d_in[0];
    const int*   ei   = (const int*)d_in[1];
    const int*   nei  = (const int*)d_in[2];
    const float* W1_0 = (const float*)d_in[3];
    const float* W1_1 = (const float*)d_in[4];
    const float* b1   = (const float*)d_in[5];
    const float* W2_0 = (const float*)d_in[6];
    const float* W2_1 = (const float*)d_in[7];
    const float* b2   = (const float*)d_in[8];
    const float* W3_0 = (const float*)d_in[9];
    const float* W3_1 = (const float*)d_in[10];
    const float* b3   = (const float*)d_in[11];
    const float* l1W  = (const float*)d_in[12];
    const float* l1b  = (const float*)d_in[13];
    const float* l2W  = (const float*)d_in[14];
    const float* l2b  = (const float*)d_in[15];
    const float* c1   = (const float*)d_in[16];
    const float* c2   = (const float*)d_in[17];
    float* out = (float*)d_out;
    float* w = (float*)d_ws;

    // workspace (float offsets)
    uint2*          cedge  = (uint2*)w;                           // 800000 int2
    int*            degs   = (int*)(w + 1600000);                 // 50000 [zeroed]
    int*            cnt    = (int*)(w + 1650000);                 // 50000 [zeroed]
    float*          dis    = w + 1700000;                         // 50000
    int*            rowptr = (int*)(w + 1750000);                 // 50001
    int*            cursor = (int*)(w + 1800008);                 // 50000
    float*          sbuf   = w + 1850008;                         // 50000
    int*            bsum   = (int*)(w + 1900008);                 // 256
    double*         red    = (double*)(w + 1900520);              // 1024 doubles
    unsigned short* xcat   = (unsigned short*)(w + 1908736);      // N*128 bf16
    unsigned short* Wt1f   = (unsigned short*)(w + 5108736);      // 40960 bf16
    unsigned short* Wt2f   = (unsigned short*)(w + 5129216);      // 66560 bf16
    unsigned short* Wtlf   = (unsigned short*)(w + 5162496);      // 13312 bf16
    float*          hp     = w + 5169152;                         // N*104 f
    unsigned char*  hwf8   = (unsigned char*)(w + 10369152);      // N*128 bytes
    float*          xm     = w + 11969152;                        // N*104 f
    unsigned char*  zf8    = (unsigned char*)(w + 17169152);      // N*128 bytes
    unsigned char*  xf8    = (unsigned char*)(w + 18769152);      // N*64 bytes
    float*          tx2    = w + 19569152;                        // N*104 f

    hipMemsetAsync(degs, 0, 100000 * sizeof(int), stream);  // degs + cnt contiguous

    // CSR build
    k_counts<<<(NE + 255) / 256, 256, 0, stream>>>(ei, degs, cnt);
    k_scan1<<<NB, 256, 0, stream>>>(cnt, degs, dis, rowptr, bsum);
    k_scan2<<<1, 256, 0, stream>>>(bsum, rowptr);
    k_scan3<<<NB, 256, 0, stream>>>(bsum, rowptr, cursor);
    k_fill<<<(NE + 255) / 256, 256, 0, stream>>>(ei, dis, cursor, cedge);

    // prep
    k_conv_x<<<NN * 64 / 256, 256, 0, stream>>>(x, xcat, xf8);
    k_prep_w<<<472, 256, 0, stream>>>(W1_0, W1_1, W2_0, W2_1, l1W, l2W, Wt1f, Wt2f, Wtlf);

    // layer 1 + 2 GEMMs (fused, h lives in LDS)
    k_gather58<<<(NN * 8 + 255) / 256, 256, 0, stream>>>(rowptr, cedge, xf8, xcat);
    k_mm12<<<(NN + 63) / 64, 256, 0, stream>>>(xcat, Wt1f, b1, Wt2f, hp, hwf8);

    // layer 2 aggregate
    k_gather100<<<NN * 16 / 256, 256, 0, stream>>>(rowptr, cedge, hwf8, tx2);

    // lin heads + x1 fusion
    k_mmlin<<<(NN + 63) / 64, 256, 0, stream>>>(xcat, Wtlf, hp, tx2, b2, l1b, l2b, xm, zf8);

    // loss
    k_score<<<SB, 256, 0, stream>>>(zf8, ei, nei, red);
    k_final<<<1, 256, 0, stream>>>(red, c1, c2, out);

    // layer 3
    k_l3<<<NN * 32 / 256, 256, 0, stream>>>(xm, W3_0, W3_1, b3, out, sbuf);
    k_gather1<<<(NN + 255) / 256, 256, 0, stream>>>(rowptr, cedge, sbuf, out);
}